// Round 6
// baseline (779.338 us; speedup 1.0000x reference)
//
#include <hip/hip_runtime.h>
#include <hip/hip_cooperative_groups.h>

#define N_NODES   20000
#define N_EDGES   640000
#define IN_DIM    128
#define HID_DIM   256
#define N_TYPES   4
#define N_ASPECTS 4096
#define NT4       (N_NODES * N_TYPES)   // 80000 CSR segments
#define NBUCK     157                   // dst buckets of 128 nodes
#define BCAP      5120                  // bucket capacity (mean 4096 + 16 sigma)
#define CHUNK     2560                  // edges per bucketA block (250 blocks exact)
#define GEMM_VB   1280                  // virtual gemm tiles (64x64, R0 mapping)
#define CLS_VB    ((N_ASPECTS * 64) / 256)

typedef __bf16 v8bf __attribute__((ext_vector_type(8)));
typedef float  f32x4 __attribute__((ext_vector_type(4)));
typedef float  v2f   __attribute__((ext_vector_type(2)));

struct P {
    const void *x, *Ws1, *Wt1, *Ws2, *Wt2, *b1, *b2, *Wc, *bc;
    const int *ei, *et, *ai;
    unsigned short *xc;
    unsigned int *xc8;
    unsigned short *WT1, *WT2;
    int *bucket_cursor;
    unsigned int *breg;
    int *flag;
    unsigned short *perm;
    int *offsets4;
    unsigned short *AG, *h, *h2;
    unsigned char *h8;
    void *out;
};

static __device__ __forceinline__ float bf2f(unsigned short u) {
    return __builtin_bit_cast(float, ((unsigned int)u) << 16);
}
static __device__ __forceinline__ float bflo(unsigned int u) {
    return __builtin_bit_cast(float, u << 16);
}
static __device__ __forceinline__ float bfhi(unsigned int u) {
    return __builtin_bit_cast(float, u & 0xffff0000u);
}
// f32 -> bf16 round-to-nearest-even (finite values)
static __device__ __forceinline__ unsigned short f2bf(float f) {
    unsigned int u = __builtin_bit_cast(unsigned int, f);
    u += 0x7fffu + ((u >> 16) & 1u);
    return (unsigned short)(u >> 16);
}

// Per-block dtype detection: 1 KB sample of W_self1.
static __device__ __forceinline__ int local_flag(const unsigned short* w, int* red) {
    int tid = threadIdx.x;
    int c = 0;
    for (int i = tid; i < 1024; i += 256) {
        unsigned hb = (w[i] >> 8) & 0x7f;
        c += (hb >= 0x39 && hb <= 0x3D) ? 1 : 0;
    }
#pragma unroll
    for (int off = 32; off >= 1; off >>= 1) c += __shfl_down(c, off);
    if ((tid & 63) == 0) red[tid >> 6] = c;
    __syncthreads();
    int tot = red[0] + red[1] + red[2] + red[3];
    __syncthreads();
    return (tot >= 768) ? 1 : 0;
}

// ---------- phase: bucketA | convx(+fp8) | packW1 | packW2 | flag ----------
static __device__ void prepA_vb(const P& p, int b, char* smem) {
    int tid = threadIdx.x;
    if (b < 250) {
        unsigned int* ord = (unsigned int*)smem;             // 2560*4 = 10240
        int* hist  = (int*)(smem + 10240);
        int* start = hist + NBUCK;
        int* cur   = start + NBUCK;
        int* gbase = cur + NBUCK;
        int* sbuf  = gbase + NBUCK;
        int e0 = b * CHUNK;
        for (int i = tid; i < NBUCK; i += 256) hist[i] = 0;
        __syncthreads();
        unsigned int pk[10];
        int bk[10];
#pragma unroll
        for (int r = 0; r < 10; r++) {
            int e = e0 + r * 256 + tid;
            int s = __builtin_nontemporal_load(p.ei + e);
            int d = __builtin_nontemporal_load(p.ei + N_EDGES + e);
            int t = __builtin_nontemporal_load(p.et + e);
            pk[r] = (unsigned int)s | ((unsigned int)t << 15) | ((unsigned int)d << 17);
            bk[r] = d >> 7;
            atomicAdd(&hist[bk[r]], 1);
        }
        __syncthreads();
        int v = (tid < NBUCK) ? hist[tid] : 0;
        sbuf[tid] = v;
        __syncthreads();
        for (int o = 1; o < 256; o <<= 1) {
            int t = (tid >= o) ? sbuf[tid - o] : 0;
            __syncthreads();
            sbuf[tid] += t;
            __syncthreads();
        }
        if (tid < NBUCK) { start[tid] = sbuf[tid] - v; cur[tid] = sbuf[tid] - v; }
        __syncthreads();
#pragma unroll
        for (int r = 0; r < 10; r++) {
            int pp = atomicAdd(&cur[bk[r]], 1);
            ord[pp] = pk[r];
        }
        __syncthreads();
        for (int bb = tid; bb < NBUCK; bb += 256)
            if (hist[bb] > 0) gbase[bb] = atomicAdd(p.bucket_cursor + bb, hist[bb]);
        __syncthreads();
        for (int pp = tid; pp < CHUNK; pp += 256) {
            unsigned int e = ord[pp];
            int bb = (int)(e >> 24);
            int gp = gbase[bb] + (pp - start[bb]);
            if (gp < BCAP)
                __builtin_nontemporal_store(e, p.breg + (size_t)bb * BCAP + gp);
        }
        __syncthreads();   // LDS WAR guard across virtual blocks
    } else if (b < 1500) {               // convx: bf16 copy + fp8 shadow
        int bf = local_flag((const unsigned short*)p.Ws1, (int*)smem);
        int idx = (b - 250) * 256 + tid;  // 8-elem chunk
        float f[8];
        if (bf) {
            uint4 v = reinterpret_cast<const uint4*>(p.x)[idx];
            reinterpret_cast<uint4*>(p.xc)[idx] = v;
            f[0] = bflo(v.x); f[1] = bfhi(v.x);
            f[2] = bflo(v.y); f[3] = bfhi(v.y);
            f[4] = bflo(v.z); f[5] = bfhi(v.z);
            f[6] = bflo(v.w); f[7] = bfhi(v.w);
        } else {
            const float* xf = reinterpret_cast<const float*>(p.x) + (size_t)idx * 8;
            unsigned short r[8] __attribute__((aligned(16)));
#pragma unroll
            for (int j = 0; j < 8; j++) { f[j] = xf[j]; r[j] = f2bf(xf[j]); }
            reinterpret_cast<uint4*>(p.xc)[idx] = *reinterpret_cast<const uint4*>(r);
        }
        int lo = 0, hi = 0;
        lo = __builtin_amdgcn_cvt_pk_fp8_f32(f[0], f[1], lo, false);
        lo = __builtin_amdgcn_cvt_pk_fp8_f32(f[2], f[3], lo, true);
        hi = __builtin_amdgcn_cvt_pk_fp8_f32(f[4], f[5], hi, false);
        hi = __builtin_amdgcn_cvt_pk_fp8_f32(f[6], f[7], hi, true);
        p.xc8[idx * 2]     = (unsigned int)lo;
        p.xc8[idx * 2 + 1] = (unsigned int)hi;
    } else if (b < 2140) {               // packW1
        int bf = local_flag((const unsigned short*)p.Ws1, (int*)smem);
        int idx = (b - 1500) * 256 + tid;
        int n = idx / 640, k = idx - n * 640;
        const void* q = (k < 128) ? p.Ws1 : p.Wt1;
        size_t src = (k < 128) ? ((size_t)k * 256 + n) : ((size_t)(k - 128) * 256 + n);
        p.WT1[idx] = bf ? ((const unsigned short*)q)[src] : f2bf(((const float*)q)[src]);
    } else if (b < 3420) {               // packW2
        int bf = local_flag((const unsigned short*)p.Ws1, (int*)smem);
        int idx = (b - 2140) * 256 + tid;
        int n = idx / 1280, k = idx - n * 1280;
        const void* q = (k < 256) ? p.Ws2 : p.Wt2;
        size_t src = (k < 256) ? ((size_t)k * 256 + n) : ((size_t)(k - 256) * 256 + n);
        p.WT2[idx] = bf ? ((const unsigned short*)q)[src] : f2bf(((const float*)q)[src]);
    } else {
        int bf = local_flag((const unsigned short*)p.Ws1, (int*)smem);
        if (tid == 0) *p.flag = bf;
    }
}

// ---------- phase: per-bucket counting sort -> perm + offsets4 -------------
static __device__ void bucketB_vb(const P& p, int b, char* smem) {
    int* cnt   = (int*)smem;        // 512 ints
    int* off   = cnt + 512;         // 512
    int* buf   = off + 512;         // 256
    int* pscan = buf + 256;         // 256  (6144 B total)
    int tid = threadIdx.x;
    int cv = (tid < NBUCK) ? p.bucket_cursor[tid] : 0;
    if (cv > BCAP) cv = BCAP;
    buf[tid] = cv;
    __syncthreads();
    for (int o = 1; o < 256; o <<= 1) {
        int t = (tid >= o) ? buf[tid - o] : 0;
        __syncthreads();
        buf[tid] += t;
        __syncthreads();
    }
    int obase = (b > 0) ? buf[b - 1] : 0;
    if (b == 0 && tid == 0) p.offsets4[NT4] = buf[255];
    int Eb = p.bucket_cursor[b];
    if (Eb > BCAP) Eb = BCAP;
    for (int i = tid; i < 512; i += 256) cnt[i] = 0;
    __syncthreads();
    const unsigned int* reg = p.breg + (size_t)b * BCAP;
    for (int i = tid; i < Eb; i += 256) {
        unsigned int e = reg[i];
        int seg = (((e >> 17) & 127) << 2) | ((e >> 15) & 3);
        atomicAdd(&cnt[seg], 1);
    }
    __syncthreads();
    int pv = cnt[2 * tid] + cnt[2 * tid + 1];
    pscan[tid] = pv;
    __syncthreads();
    for (int o = 1; o < 256; o <<= 1) {
        int t = (tid >= o) ? pscan[tid - o] : 0;
        __syncthreads();
        pscan[tid] += t;
        __syncthreads();
    }
    int pexcl = pscan[tid] - pv;
    off[2 * tid]     = pexcl;
    off[2 * tid + 1] = pexcl + cnt[2 * tid];
    __syncthreads();
    for (int i = tid; i < 512; i += 256) {
        int node = b * 128 + (i >> 2);
        if (node < N_NODES) p.offsets4[node * 4 + (i & 3)] = obase + off[i];
    }
    __syncthreads();
    for (int i = tid; i < Eb; i += 256) {
        unsigned int e = reg[i];
        int seg = (((e >> 17) & 127) << 2) | ((e >> 15) & 3);
        int pp = atomicAdd(&off[seg], 1);
        p.perm[obase + pp] = (unsigned short)(e & 0x7fff);
    }
    __syncthreads();   // LDS WAR guard across virtual buckets
}

// ---------- phase: typed aggregation (fp8 gather, f32 accumulate) ----------
template <int D>
static __device__ void agg8_body(const unsigned int* __restrict__ F8,
                                 const int* __restrict__ offs4,
                                 const unsigned short* __restrict__ perm,
                                 unsigned short* __restrict__ AG) {
    constexpr int G = D / 8;                     // 16 (D=128) or 32 (D=256)
    constexpr int NSUB = 64 / G;                 // 4 or 2
    int wave = threadIdx.x >> 6, lane = threadIdx.x & 63;
    int sg = lane / G;
    int gl = lane - sg * G;
    for (int n = blockIdx.x * 4 + wave; n < N_NODES; n += gridDim.x * 4) {
        int o0 = offs4[n * 4];
        int o4 = offs4[n * 4 + 4];
        int deg = o4 - o0;
        float inv = 1.0f / (float)(deg > 1 ? deg : 1);
        int s0 = o0;
#pragma unroll
        for (int t = 0; t < 4; t++) {
            int s1 = offs4[n * 4 + t + 1];
            float a[8];
#pragma unroll
            for (int v = 0; v < 8; v++) a[v] = 0.f;
            int j = s0;
            while (j < s1) {
                int m = s1 - j;
                if (m > 64) m = 64;
                int pw = (int)perm[j + ((lane < m) ? lane : 0)];
                int nfull = (m / (NSUB * 4)) * (NSUB * 4);
                for (int base = 0; base < nfull; base += NSUB * 4) {
                    uint2 xv[4];
#pragma unroll
                    for (int l = 0; l < 4; l++) {
                        int src = __shfl(pw, base + sg * 4 + l);
                        xv[l] = *reinterpret_cast<const uint2*>(F8 + (size_t)src * (D / 4) + gl * 2);
                    }
#pragma unroll
                    for (int l = 0; l < 4; l++) {
                        v2f p0 = __builtin_amdgcn_cvt_pk_f32_fp8((int)xv[l].x, false);
                        v2f p1 = __builtin_amdgcn_cvt_pk_f32_fp8((int)xv[l].x, true);
                        v2f p2 = __builtin_amdgcn_cvt_pk_f32_fp8((int)xv[l].y, false);
                        v2f p3 = __builtin_amdgcn_cvt_pk_f32_fp8((int)xv[l].y, true);
                        a[0] += p0.x; a[1] += p0.y;
                        a[2] += p1.x; a[3] += p1.y;
                        a[4] += p2.x; a[5] += p2.y;
                        a[6] += p3.x; a[7] += p3.y;
                    }
                }
                for (int k = nfull; k < m; k += NSUB) {
                    int e = k + sg;
                    int valid = (e < m);
                    int idx = valid ? e : (m - 1);
                    int src = __shfl(pw, idx);
                    uint2 xv = *reinterpret_cast<const uint2*>(F8 + (size_t)src * (D / 4) + gl * 2);
                    unsigned msk = valid ? 0xffffffffu : 0u;  // fp8 0x00 == +0.0
                    xv.x &= msk; xv.y &= msk;
                    v2f p0 = __builtin_amdgcn_cvt_pk_f32_fp8((int)xv.x, false);
                    v2f p1 = __builtin_amdgcn_cvt_pk_f32_fp8((int)xv.x, true);
                    v2f p2 = __builtin_amdgcn_cvt_pk_f32_fp8((int)xv.y, false);
                    v2f p3 = __builtin_amdgcn_cvt_pk_f32_fp8((int)xv.y, true);
                    a[0] += p0.x; a[1] += p0.y;
                    a[2] += p1.x; a[3] += p1.y;
                    a[4] += p2.x; a[5] += p2.y;
                    a[6] += p3.x; a[7] += p3.y;
                }
                j += m;
            }
#pragma unroll
            for (int v = 0; v < 8; v++) {
                float s = a[v];
                s += __shfl_xor(s, G);
                if (NSUB == 4) s += __shfl_xor(s, 2 * G);
                a[v] = s * inv;
            }
            if (sg == 0) {
                unsigned short r[8] __attribute__((aligned(16)));
#pragma unroll
                for (int v = 0; v < 8; v++) r[v] = f2bf(a[v]);
                *reinterpret_cast<uint4*>(AG + (size_t)n * (4 * D) + t * D + gl * 8) =
                    *reinterpret_cast<const uint4*>(r);
            }
            s0 = s1;
        }
    }
}

// ---------- phase: MFMA GEMM (R0 structure: 64x64 tile, 1280 vtiles) -------
template <int D>
static __device__ void gemm_vb(char* smem,
        const unsigned short* __restrict__ X,
        const unsigned short* __restrict__ AG,
        const unsigned short* __restrict__ BT,
        const void* __restrict__ bias,
        const int* __restrict__ flagp,
        unsigned short* __restrict__ C,
        unsigned char* __restrict__ C8,
        int M, int relu, int b) {
    constexpr int K = 5 * D;
    constexpr int LDW = 72;
    unsigned short* As = (unsigned short*)smem;      // 64*72*2 = 9216 B
    unsigned short* Bs = As + 64 * LDW;              // total 18432 B
    int mt = (b & 7) + 8 * (b >> 5);
    int nt = (b >> 3) & 3;
    int mtiles = (M + 63) >> 6;
    if (mt >= mtiles) return;
    int m0 = mt * 64;
    int n0 = nt * 64;
    int tid  = threadIdx.x;
    int wave = tid >> 6, lane = tid & 63;
    int wm = wave >> 1, wn = wave & 1;
    int quad = lane >> 4, l16 = lane & 15;

    f32x4 acc[2][2];
#pragma unroll
    for (int i = 0; i < 2; i++)
#pragma unroll
        for (int j = 0; j < 2; j++) acc[i][j] = (f32x4){0.f, 0.f, 0.f, 0.f};

    for (int k0 = 0; k0 < K; k0 += 64) {
        const unsigned short* base = (k0 < D) ? X : AG;
        int rs  = (k0 < D) ? D : 4 * D;
        int col = (k0 < D) ? k0 : (k0 - D);
#pragma unroll
        for (int cc = 0; cc < 2; cc++) {
            int c   = tid + cc * 256;
            int row = c >> 3;
            int c8  = c & 7;
            uint4 va = make_uint4(0u, 0u, 0u, 0u);
            int gr = m0 + row;
            if (gr < M)
                va = *reinterpret_cast<const uint4*>(base + (size_t)gr * rs + col + c8 * 8);
            *reinterpret_cast<uint4*>(&As[row * LDW + c8 * 8]) = va;
            uint4 vb = *reinterpret_cast<const uint4*>(BT + (size_t)(n0 + row) * K + k0 + c8 * 8);
            *reinterpret_cast<uint4*>(&Bs[row * LDW + c8 * 8]) = vb;
        }
        __syncthreads();
#pragma unroll
        for (int ks = 0; ks < 2; ks++) {
            v8bf af[2], bfr[2];
#pragma unroll
            for (int i = 0; i < 2; i++)
                af[i] = *reinterpret_cast<const v8bf*>(
                    &As[(wm * 32 + i * 16 + l16) * LDW + ks * 32 + quad * 8]);
#pragma unroll
            for (int j = 0; j < 2; j++)
                bfr[j] = *reinterpret_cast<const v8bf*>(
                    &Bs[(wn * 32 + j * 16 + l16) * LDW + ks * 32 + quad * 8]);
#pragma unroll
            for (int i = 0; i < 2; i++)
#pragma unroll
                for (int j = 0; j < 2; j++)
                    acc[i][j] = __builtin_amdgcn_mfma_f32_16x16x32_bf16(af[i], bfr[j], acc[i][j], 0, 0, 0);
        }
        __syncthreads();
    }
    int bf = *flagp;
#pragma unroll
    for (int i = 0; i < 2; i++) {
#pragma unroll
        for (int j = 0; j < 2; j++) {
            int col = n0 + wn * 32 + j * 16 + l16;
            float bv = bf ? bf2f(((const unsigned short*)bias)[col])
                          : ((const float*)bias)[col];
#pragma unroll
            for (int r = 0; r < 4; r++) {
                int row = m0 + wm * 32 + i * 16 + quad * 4 + r;
                if (row < M) {
                    float v = acc[i][j][r] + bv;
                    if (relu) v = fmaxf(v, 0.0f);
                    C[(size_t)row * 256 + col] = f2bf(v);
                    if (C8) {
                        int pk = __builtin_amdgcn_cvt_pk_fp8_f32(v, v, 0, false);
                        C8[(size_t)row * 256 + col] = (unsigned char)(pk & 0xff);
                    }
                }
            }
        }
    }
}

// ---------- phase: classifier head -----------------------------------------
static __device__ void cls_vb(const P& p, int vb) {
    int lin = vb * 256 + threadIdx.x;
    int a = lin >> 6, lane = lin & 63;
    if (a >= N_ASPECTS) return;
    int bf = *p.flag;
    int node = p.ai[a];
    uint2 v = *reinterpret_cast<const uint2*>(p.h2 + (size_t)node * 256 + lane * 4);
    float hv[4] = {bflo(v.x), bfhi(v.x), bflo(v.y), bfhi(v.y)};
    float a0 = 0.f, a1 = 0.f, a2 = 0.f;
#pragma unroll
    for (int r = 0; r < 4; r++) {
        int k = lane * 4 + r;
        float w0 = bf ? bf2f(((const unsigned short*)p.Wc)[k * 3 + 0]) : ((const float*)p.Wc)[k * 3 + 0];
        float w1 = bf ? bf2f(((const unsigned short*)p.Wc)[k * 3 + 1]) : ((const float*)p.Wc)[k * 3 + 1];
        float w2 = bf ? bf2f(((const unsigned short*)p.Wc)[k * 3 + 2]) : ((const float*)p.Wc)[k * 3 + 2];
        a0 += hv[r] * w0;
        a1 += hv[r] * w1;
        a2 += hv[r] * w2;
    }
#pragma unroll
    for (int off = 32; off >= 1; off >>= 1) {
        a0 += __shfl_down(a0, off);
        a1 += __shfl_down(a1, off);
        a2 += __shfl_down(a2, off);
    }
    if (lane == 0) {
        float b0 = bf ? bf2f(((const unsigned short*)p.bc)[0]) : ((const float*)p.bc)[0];
        float b1 = bf ? bf2f(((const unsigned short*)p.bc)[1]) : ((const float*)p.bc)[1];
        float b2 = bf ? bf2f(((const unsigned short*)p.bc)[2]) : ((const float*)p.bc)[2];
        if (bf) {
            unsigned short* o = (unsigned short*)p.out;
            o[a * 3 + 0] = f2bf(a0 + b0);
            o[a * 3 + 1] = f2bf(a1 + b1);
            o[a * 3 + 2] = f2bf(a2 + b2);
        } else {
            float* o = (float*)p.out;
            o[a * 3 + 0] = a0 + b0;
            o[a * 3 + 1] = a1 + b1;
            o[a * 3 + 2] = a2 + b2;
        }
    }
}

// ---------- mega: one cooperative kernel, grid.sync between phases ---------
__global__ __launch_bounds__(256) void mega_kernel(P p) {
    __shared__ __align__(16) char smem[18432];
    cooperative_groups::grid_group g = cooperative_groups::this_grid();
    if (blockIdx.x == 0 && threadIdx.x < NBUCK) p.bucket_cursor[threadIdx.x] = 0;
    g.sync();
    for (int b = blockIdx.x; b < 3421; b += gridDim.x) prepA_vb(p, b, smem);
    g.sync();
    for (int b = blockIdx.x; b < NBUCK; b += gridDim.x) bucketB_vb(p, b, smem);
    g.sync();
    agg8_body<IN_DIM>(p.xc8, p.offsets4, p.perm, p.AG);
    g.sync();
    for (int b = blockIdx.x; b < GEMM_VB; b += gridDim.x)
        gemm_vb<IN_DIM>(smem, p.xc, p.AG, p.WT1, p.b1, p.flag, p.h, p.h8, N_NODES, 1, b);
    g.sync();
    agg8_body<HID_DIM>((const unsigned int*)p.h8, p.offsets4, p.perm, p.AG);
    g.sync();
    for (int b = blockIdx.x; b < GEMM_VB; b += gridDim.x)
        gemm_vb<HID_DIM>(smem, p.h, p.AG, p.WT2, p.b2, p.flag, p.h2, nullptr, N_NODES, 0, b);
    g.sync();
    for (int vb = blockIdx.x; vb < CLS_VB; vb += gridDim.x) cls_vb(p, vb);
}

// ---------- fallback wrappers (8-dispatch path, identical device code) -----
__global__ __launch_bounds__(256) void prepA_kernel(P p) {
    __shared__ __align__(16) char smem[14336];
    prepA_vb(p, blockIdx.x, smem);
}
__global__ __launch_bounds__(256) void bucketB_kernel(P p) {
    __shared__ __align__(16) char smem[6144];
    bucketB_vb(p, blockIdx.x, smem);
}
template <int D>
__global__ __launch_bounds__(256) void agg8_kernel(const unsigned int* F8, const int* o,
                                                   const unsigned short* pm, unsigned short* AG) {
    agg8_body<D>(F8, o, pm, AG);
}
template <int D>
__global__ __launch_bounds__(256) void gemm_kernel(const unsigned short* X, const unsigned short* AG,
                                                   const unsigned short* BT, const void* bias,
                                                   const int* flagp, unsigned short* C,
                                                   unsigned char* C8, int M, int relu) {
    __shared__ __align__(16) char smem[18432];
    gemm_vb<D>(smem, X, AG, BT, bias, flagp, C, C8, M, relu, blockIdx.x);
}
__global__ void cls_kernel(P p) { cls_vb(p, blockIdx.x); }

extern "C" void kernel_launch(void* const* d_in, const int* in_sizes, int n_in,
                              void* d_out, int out_size, void* d_ws, size_t ws_size,
                              hipStream_t stream) {
    char* ws = (char*)d_ws;
    size_t off = 0;
    auto alloc = [&](size_t bytes) {
        void* q = ws + off;
        off += (bytes + 255) & ~(size_t)255;
        return q;
    };
    P p;
    p.x   = d_in[0];  p.Wt1 = d_in[1];  p.Ws1 = d_in[2];  p.b1 = d_in[3];
    p.Wt2 = d_in[4];  p.Ws2 = d_in[5];  p.b2  = d_in[6];
    p.Wc  = d_in[7];  p.bc  = d_in[8];
    p.ei  = (const int*)d_in[9];
    p.et  = (const int*)d_in[10];
    p.ai  = (const int*)d_in[11];
    p.out = d_out;
    p.flag          = (int*)alloc(4);
    p.bucket_cursor = (int*)alloc((size_t)NBUCK * 4);
    p.offsets4      = (int*)alloc((size_t)(NT4 + 1) * 4);
    p.breg          = (unsigned int*)alloc((size_t)NBUCK * BCAP * 4);
    p.perm          = (unsigned short*)alloc((size_t)N_EDGES * 2);
    p.xc            = (unsigned short*)alloc((size_t)N_NODES * IN_DIM * 2);
    p.xc8           = (unsigned int*)alloc((size_t)N_NODES * IN_DIM);
    p.AG            = (unsigned short*)alloc((size_t)N_NODES * 4 * HID_DIM * 2);
    p.h             = (unsigned short*)alloc((size_t)N_NODES * HID_DIM * 2);
    p.h8            = (unsigned char*)alloc((size_t)N_NODES * HID_DIM);
    p.h2            = (unsigned short*)alloc((size_t)N_NODES * HID_DIM * 2);
    p.WT1           = (unsigned short*)alloc((size_t)640 * 256 * 2);
    p.WT2           = (unsigned short*)alloc((size_t)1280 * 256 * 2);

    static int coop_grid = 0;
    if (coop_grid == 0) {
        int nb = 0;
        if (hipOccupancyMaxActiveBlocksPerMultiprocessor(&nb, (const void*)mega_kernel, 256, 0)
                != hipSuccess || nb < 1)
            nb = 2;
        int gsz = nb * 256;                 // 256 CUs on MI355X
        if (gsz > GEMM_VB) gsz = GEMM_VB;
        if (gsz < 256)     gsz = 256;
        coop_grid = gsz;
    }
    void* args[] = {(void*)&p};
    hipError_t e = hipLaunchCooperativeKernel((const void*)mega_kernel,
                                              dim3(coop_grid), dim3(256), args, 0, stream);
    if (e != hipSuccess) {
        (void)hipGetLastError();            // clear, fall back to 8-dispatch path
        hipMemsetAsync(p.bucket_cursor, 0, (size_t)NBUCK * 4, stream);
        prepA_kernel<<<3421, 256, 0, stream>>>(p);
        bucketB_kernel<<<NBUCK, 256, 0, stream>>>(p);
        agg8_kernel<IN_DIM><<<4096, 256, 0, stream>>>(p.xc8, p.offsets4, p.perm, p.AG);
        gemm_kernel<IN_DIM><<<GEMM_VB, 256, 0, stream>>>(p.xc, p.AG, p.WT1, p.b1, p.flag,
                                                         p.h, p.h8, N_NODES, 1);
        agg8_kernel<HID_DIM><<<4096, 256, 0, stream>>>((const unsigned int*)p.h8, p.offsets4,
                                                       p.perm, p.AG);
        gemm_kernel<HID_DIM><<<GEMM_VB, 256, 0, stream>>>(p.h, p.AG, p.WT2, p.b2, p.flag,
                                                          p.h2, nullptr, N_NODES, 0);
        cls_kernel<<<CLS_VB, 256, 0, stream>>>(p);
    }
}

// Round 7
// 273.491 us; speedup vs baseline: 2.8496x; 2.8496x over previous
//
#include <hip/hip_runtime.h>

#define N_NODES   20000
#define N_EDGES   640000
#define IN_DIM    128
#define HID_DIM   256
#define N_TYPES   4
#define N_ASPECTS 4096
#define NT4       (N_NODES * N_TYPES)   // 80000 CSR segments
#define NBUCK     157                   // dst buckets of 128 nodes
#define BCAP      5120                  // bucket capacity (mean 4096 + 16 sigma)
#define CHUNK     2560                  // edges per bucketA block (250 blocks exact)

typedef __bf16 v8bf __attribute__((ext_vector_type(8)));
typedef float  f32x4 __attribute__((ext_vector_type(4)));
typedef float  v2f   __attribute__((ext_vector_type(2)));

static __device__ __forceinline__ float bf2f(unsigned short u) {
    return __builtin_bit_cast(float, ((unsigned int)u) << 16);
}
static __device__ __forceinline__ float bflo(unsigned int u) {
    return __builtin_bit_cast(float, u << 16);
}
static __device__ __forceinline__ float bfhi(unsigned int u) {
    return __builtin_bit_cast(float, u & 0xffff0000u);
}
// f32 -> bf16 round-to-nearest-even (finite values)
static __device__ __forceinline__ unsigned short f2bf(float f) {
    unsigned int u = __builtin_bit_cast(unsigned int, f);
    u += 0x7fffu + ((u >> 16) & 1u);
    return (unsigned short)(u >> 16);
}

// Per-block dtype detection: 1 KB sample of W_self1.
static __device__ __forceinline__ int local_flag(const unsigned short* w, int* red) {
    int tid = threadIdx.x;
    int c = 0;
    for (int i = tid; i < 1024; i += 256) {
        unsigned hb = (w[i] >> 8) & 0x7f;
        c += (hb >= 0x39 && hb <= 0x3D) ? 1 : 0;
    }
#pragma unroll
    for (int off = 32; off >= 1; off >>= 1) c += __shfl_down(c, off);
    if ((tid & 63) == 0) red[tid >> 6] = c;
    __syncthreads();
    int tot = red[0] + red[1] + red[2] + red[3];
    __syncthreads();
    return (tot >= 768) ? 1 : 0;
}

// ---------- fused: bucketA | convx(+fp8) | packW1 | packW2 | flag ----------
__global__ __launch_bounds__(256) void prepA_kernel(
        const void* __restrict__ x,
        const void* __restrict__ Ws1, const void* __restrict__ Wt1,
        const void* __restrict__ Ws2, const void* __restrict__ Wt2,
        const int* __restrict__ ei, const int* __restrict__ et,
        unsigned short* __restrict__ xc,
        unsigned int* __restrict__ xc8,
        unsigned short* __restrict__ WT1,
        unsigned short* __restrict__ WT2,
        int* __restrict__ bucket_cursor,
        unsigned int* __restrict__ breg,
        int* __restrict__ flag) {
    __shared__ __align__(16) char smem[14336];
    int b = blockIdx.x, tid = threadIdx.x;
    if (b < 250) {
        unsigned int* ord = (unsigned int*)smem;             // 2560*4 = 10240
        int* hist  = (int*)(smem + 10240);
        int* start = hist + NBUCK;
        int* cur   = start + NBUCK;
        int* gbase = cur + NBUCK;
        int* sbuf  = gbase + NBUCK;
        int e0 = b * CHUNK;
        for (int i = tid; i < NBUCK; i += 256) hist[i] = 0;
        __syncthreads();
        unsigned int pk[10];
        int bk[10];
#pragma unroll
        for (int r = 0; r < 10; r++) {
            int e = e0 + r * 256 + tid;
            int s = __builtin_nontemporal_load(ei + e);
            int d = __builtin_nontemporal_load(ei + N_EDGES + e);
            int t = __builtin_nontemporal_load(et + e);
            pk[r] = (unsigned int)s | ((unsigned int)t << 15) | ((unsigned int)d << 17);
            bk[r] = d >> 7;
            atomicAdd(&hist[bk[r]], 1);
        }
        __syncthreads();
        int v = (tid < NBUCK) ? hist[tid] : 0;
        sbuf[tid] = v;
        __syncthreads();
        for (int o = 1; o < 256; o <<= 1) {
            int t = (tid >= o) ? sbuf[tid - o] : 0;
            __syncthreads();
            sbuf[tid] += t;
            __syncthreads();
        }
        if (tid < NBUCK) { start[tid] = sbuf[tid] - v; cur[tid] = sbuf[tid] - v; }
        __syncthreads();
#pragma unroll
        for (int r = 0; r < 10; r++) {
            int p = atomicAdd(&cur[bk[r]], 1);
            ord[p] = pk[r];
        }
        __syncthreads();
        for (int bb = tid; bb < NBUCK; bb += 256)
            if (hist[bb] > 0) gbase[bb] = atomicAdd(bucket_cursor + bb, hist[bb]);
        __syncthreads();
        for (int p = tid; p < CHUNK; p += 256) {
            unsigned int e = ord[p];
            int bb = (int)(e >> 24);
            int gp = gbase[bb] + (p - start[bb]);
            if (gp < BCAP)
                __builtin_nontemporal_store(e, breg + (size_t)bb * BCAP + gp);
        }
    } else if (b < 1500) {               // convx: bf16 copy + fp8 shadow
        int bf = local_flag((const unsigned short*)Ws1, (int*)smem);
        int idx = (b - 250) * 256 + tid;  // 8-elem chunk
        float f[8];
        if (bf) {
            uint4 v = reinterpret_cast<const uint4*>(x)[idx];
            reinterpret_cast<uint4*>(xc)[idx] = v;
            f[0] = bflo(v.x); f[1] = bfhi(v.x);
            f[2] = bflo(v.y); f[3] = bfhi(v.y);
            f[4] = bflo(v.z); f[5] = bfhi(v.z);
            f[6] = bflo(v.w); f[7] = bfhi(v.w);
        } else {
            const float* xf = reinterpret_cast<const float*>(x) + (size_t)idx * 8;
            unsigned short r[8] __attribute__((aligned(16)));
#pragma unroll
            for (int j = 0; j < 8; j++) { f[j] = xf[j]; r[j] = f2bf(xf[j]); }
            reinterpret_cast<uint4*>(xc)[idx] = *reinterpret_cast<const uint4*>(r);
        }
        int lo = 0, hi = 0;
        lo = __builtin_amdgcn_cvt_pk_fp8_f32(f[0], f[1], lo, false);
        lo = __builtin_amdgcn_cvt_pk_fp8_f32(f[2], f[3], lo, true);
        hi = __builtin_amdgcn_cvt_pk_fp8_f32(f[4], f[5], hi, false);
        hi = __builtin_amdgcn_cvt_pk_fp8_f32(f[6], f[7], hi, true);
        xc8[idx * 2]     = (unsigned int)lo;
        xc8[idx * 2 + 1] = (unsigned int)hi;
    } else if (b < 2140) {               // packW1
        int bf = local_flag((const unsigned short*)Ws1, (int*)smem);
        int idx = (b - 1500) * 256 + tid;
        int n = idx / 640, k = idx - n * 640;
        const void* p = (k < 128) ? Ws1 : Wt1;
        size_t src = (k < 128) ? ((size_t)k * 256 + n) : ((size_t)(k - 128) * 256 + n);
        WT1[idx] = bf ? ((const unsigned short*)p)[src] : f2bf(((const float*)p)[src]);
    } else if (b < 3420) {               // packW2
        int bf = local_flag((const unsigned short*)Ws1, (int*)smem);
        int idx = (b - 2140) * 256 + tid;
        int n = idx / 1280, k = idx - n * 1280;
        const void* p = (k < 256) ? Ws2 : Wt2;
        size_t src = (k < 256) ? ((size_t)k * 256 + n) : ((size_t)(k - 256) * 256 + n);
        WT2[idx] = bf ? ((const unsigned short*)p)[src] : f2bf(((const float*)p)[src]);
    } else {
        int bf = local_flag((const unsigned short*)Ws1, (int*)smem);
        if (tid == 0) *flag = bf;
    }
}

// Pass B: per-bucket counting sort -> perm + offsets4 (parallel scans).
__global__ __launch_bounds__(256) void bucketB_kernel(
        const unsigned int* __restrict__ breg,
        const int* __restrict__ bucket_cursor,
        unsigned short* __restrict__ perm,
        int* __restrict__ offsets4) {
    __shared__ int cnt[512], off[512];
    __shared__ int buf[256], pscan[256];
    int b = blockIdx.x, tid = threadIdx.x;
    int cv = (tid < NBUCK) ? bucket_cursor[tid] : 0;
    if (cv > BCAP) cv = BCAP;
    buf[tid] = cv;
    __syncthreads();
    for (int o = 1; o < 256; o <<= 1) {
        int t = (tid >= o) ? buf[tid - o] : 0;
        __syncthreads();
        buf[tid] += t;
        __syncthreads();
    }
    int obase = (b > 0) ? buf[b - 1] : 0;
    if (b == 0 && tid == 0) offsets4[NT4] = buf[255];
    int Eb = bucket_cursor[b];
    if (Eb > BCAP) Eb = BCAP;
    for (int i = tid; i < 512; i += 256) cnt[i] = 0;
    __syncthreads();
    const unsigned int* reg = breg + (size_t)b * BCAP;
    for (int i = tid; i < Eb; i += 256) {
        unsigned int e = reg[i];
        int seg = (((e >> 17) & 127) << 2) | ((e >> 15) & 3);
        atomicAdd(&cnt[seg], 1);
    }
    __syncthreads();
    int pv = cnt[2 * tid] + cnt[2 * tid + 1];
    pscan[tid] = pv;
    __syncthreads();
    for (int o = 1; o < 256; o <<= 1) {
        int t = (tid >= o) ? pscan[tid - o] : 0;
        __syncthreads();
        pscan[tid] += t;
        __syncthreads();
    }
    int pexcl = pscan[tid] - pv;
    off[2 * tid]     = pexcl;
    off[2 * tid + 1] = pexcl + cnt[2 * tid];
    __syncthreads();
    for (int i = tid; i < 512; i += 256) {
        int node = b * 128 + (i >> 2);
        if (node < N_NODES) offsets4[node * 4 + (i & 3)] = obase + off[i];
    }
    __syncthreads();
    for (int i = tid; i < Eb; i += 256) {
        unsigned int e = reg[i];
        int seg = (((e >> 17) & 127) << 2) | ((e >> 15) & 3);
        int p = atomicAdd(&off[seg], 1);
        perm[obase + p] = (unsigned short)(e & 0x7fff);
    }
}

// ---------- typed aggregation: fp8 gather (uint4), f32 accumulate ----------
// R22: 16B/lane loads. Subgroup of G = D/16 lanes each loading uint4
// (16 fp8); NSUB = 64/G subgroups gather independent edges, ILP4 ->
// 2x edges in flight vs the uint2 version (gather is request-rate-bound
// at the LLC: h8 = 5.1 MB > 4 MB per-XCD L2). Wave-uniform tail.
static __device__ __forceinline__ void acc16(uint4 x, float* a) {
    v2f p;
    p = __builtin_amdgcn_cvt_pk_f32_fp8((int)x.x, false); a[0]  += p.x; a[1]  += p.y;
    p = __builtin_amdgcn_cvt_pk_f32_fp8((int)x.x, true);  a[2]  += p.x; a[3]  += p.y;
    p = __builtin_amdgcn_cvt_pk_f32_fp8((int)x.y, false); a[4]  += p.x; a[5]  += p.y;
    p = __builtin_amdgcn_cvt_pk_f32_fp8((int)x.y, true);  a[6]  += p.x; a[7]  += p.y;
    p = __builtin_amdgcn_cvt_pk_f32_fp8((int)x.z, false); a[8]  += p.x; a[9]  += p.y;
    p = __builtin_amdgcn_cvt_pk_f32_fp8((int)x.z, true);  a[10] += p.x; a[11] += p.y;
    p = __builtin_amdgcn_cvt_pk_f32_fp8((int)x.w, false); a[12] += p.x; a[13] += p.y;
    p = __builtin_amdgcn_cvt_pk_f32_fp8((int)x.w, true);  a[14] += p.x; a[15] += p.y;
}

template <int D>
__global__ __launch_bounds__(256) void agg8_kernel(
        const unsigned int* __restrict__ F8,     // [N, D] fp8 (uint-chunked)
        const int* __restrict__ offs4,
        const unsigned short* __restrict__ perm,
        unsigned short* __restrict__ AG) {       // [N, 4*D] bf16
    constexpr int G = D / 16;                    // 8 (D=128) or 16 (D=256)
    constexpr int NSUB = 64 / G;                 // 8 or 4
    int wave = threadIdx.x >> 6, lane = threadIdx.x & 63;
    int sg = lane / G;
    int gl = lane - sg * G;
    for (int n = blockIdx.x * 4 + wave; n < N_NODES; n += gridDim.x * 4) {
        int o0 = offs4[n * 4];
        int o4 = offs4[n * 4 + 4];
        int deg = o4 - o0;
        float inv = 1.0f / (float)(deg > 1 ? deg : 1);
        int s0 = o0;
#pragma unroll
        for (int t = 0; t < 4; t++) {
            int s1 = offs4[n * 4 + t + 1];
            float a[16];
#pragma unroll
            for (int v = 0; v < 16; v++) a[v] = 0.f;
            int j = s0;
            while (j < s1) {
                int m = s1 - j;
                if (m > 64) m = 64;
                int pw = (int)perm[j + ((lane < m) ? lane : 0)];
                int nfull = (m / (NSUB * 4)) * (NSUB * 4);
                for (int base = 0; base < nfull; base += NSUB * 4) {
                    uint4 x[4];
#pragma unroll
                    for (int l = 0; l < 4; l++) {
                        int src = __shfl(pw, base + sg * 4 + l);
                        x[l] = *reinterpret_cast<const uint4*>(F8 + (size_t)src * (D / 4) + gl * 4);
                    }
#pragma unroll
                    for (int l = 0; l < 4; l++) acc16(x[l], a);
                }
                for (int k = nfull; k < m; k += NSUB) {
                    int e = k + sg;
                    int valid = (e < m);
                    int idx = valid ? e : (m - 1);
                    int src = __shfl(pw, idx);
                    uint4 x = *reinterpret_cast<const uint4*>(F8 + (size_t)src * (D / 4) + gl * 4);
                    unsigned msk = valid ? 0xffffffffu : 0u;  // fp8 0x00 == +0.0
                    x.x &= msk; x.y &= msk; x.z &= msk; x.w &= msk;
                    acc16(x, a);
                }
                j += m;
            }
#pragma unroll
            for (int v = 0; v < 16; v++) {
                float s = a[v];
                s += __shfl_xor(s, G);
                s += __shfl_xor(s, 2 * G);
                if (NSUB == 8) s += __shfl_xor(s, 4 * G);
                a[v] = s * inv;
            }
            if (sg == 0) {
                unsigned short r[16] __attribute__((aligned(16)));
#pragma unroll
                for (int v = 0; v < 16; v++) r[v] = f2bf(a[v]);
                unsigned short* dst = AG + (size_t)n * (4 * D) + t * D + gl * 16;
                *reinterpret_cast<uint4*>(dst)     = reinterpret_cast<const uint4*>(r)[0];
                *reinterpret_cast<uint4*>(dst + 8) = reinterpret_cast<const uint4*>(r)[1];
            }
            s0 = s1;
        }
    }
}

// ---------- MFMA GEMM: C[M,256] = [X | AG] @ WT^T + bias -------------------
// R0 structure (best measured): 64x64 tile, XCD swizzle, LDW=72 padded LDS,
// grid 1280. Optional fp8 shadow emission of C (post-activation).
template <int D>
__global__ __launch_bounds__(256, 6) void gemm_kernel(
        const unsigned short* __restrict__ X,
        const unsigned short* __restrict__ AG,
        const unsigned short* __restrict__ BT,
        const void* __restrict__ bias,
        const int* __restrict__ flagp,
        unsigned short* __restrict__ C,
        unsigned char* __restrict__ C8,          // fp8 shadow (or nullptr)
        int M, int relu) {
    constexpr int K = 5 * D;
    constexpr int LDW = 72;
    __shared__ __align__(16) unsigned short As[64 * LDW];
    __shared__ __align__(16) unsigned short Bs[64 * LDW];
    int b = blockIdx.x;
    int mt = (b & 7) + 8 * (b >> 5);
    int nt = (b >> 3) & 3;
    int mtiles = (M + 63) >> 6;
    if (mt >= mtiles) return;
    int m0 = mt * 64;
    int n0 = nt * 64;
    int tid  = threadIdx.x;
    int wave = tid >> 6, lane = tid & 63;
    int wm = wave >> 1, wn = wave & 1;
    int quad = lane >> 4, l16 = lane & 15;

    f32x4 acc[2][2];
#pragma unroll
    for (int i = 0; i < 2; i++)
#pragma unroll
        for (int j = 0; j < 2; j++) acc[i][j] = (f32x4){0.f, 0.f, 0.f, 0.f};

    for (int k0 = 0; k0 < K; k0 += 64) {
        const unsigned short* base = (k0 < D) ? X : AG;
        int rs  = (k0 < D) ? D : 4 * D;
        int col = (k0 < D) ? k0 : (k0 - D);
#pragma unroll
        for (int cc = 0; cc < 2; cc++) {
            int c   = tid + cc * 256;
            int row = c >> 3;
            int c8  = c & 7;
            uint4 va = make_uint4(0u, 0u, 0u, 0u);
            int gr = m0 + row;
            if (gr < M)
                va = *reinterpret_cast<const uint4*>(base + (size_t)gr * rs + col + c8 * 8);
            *reinterpret_cast<uint4*>(&As[row * LDW + c8 * 8]) = va;
            uint4 vb = *reinterpret_cast<const uint4*>(BT + (size_t)(n0 + row) * K + k0 + c8 * 8);
            *reinterpret_cast<uint4*>(&Bs[row * LDW + c8 * 8]) = vb;
        }
        __syncthreads();
#pragma unroll
        for (int ks = 0; ks < 2; ks++) {
            v8bf af[2], bfr[2];
#pragma unroll
            for (int i = 0; i < 2; i++)
                af[i] = *reinterpret_cast<const v8bf*>(
                    &As[(wm * 32 + i * 16 + l16) * LDW + ks * 32 + quad * 8]);
#pragma unroll
            for (int j = 0; j < 2; j++)
                bfr[j] = *reinterpret_cast<const v8bf*>(
                    &Bs[(wn * 32 + j * 16 + l16) * LDW + ks * 32 + quad * 8]);
#pragma unroll
            for (int i = 0; i < 2; i++)
#pragma unroll
                for (int j = 0; j < 2; j++)
                    acc[i][j] = __builtin_amdgcn_mfma_f32_16x16x32_bf16(af[i], bfr[j], acc[i][j], 0, 0, 0);
        }
        __syncthreads();
    }
    int bf = *flagp;
#pragma unroll
    for (int i = 0; i < 2; i++) {
#pragma unroll
        for (int j = 0; j < 2; j++) {
            int col = n0 + wn * 32 + j * 16 + l16;
            float bv = bf ? bf2f(((const unsigned short*)bias)[col])
                          : ((const float*)bias)[col];
#pragma unroll
            for (int r = 0; r < 4; r++) {
                int row = m0 + wm * 32 + i * 16 + quad * 4 + r;
                if (row < M) {
                    float v = acc[i][j][r] + bv;
                    if (relu) v = fmaxf(v, 0.0f);
                    C[(size_t)row * 256 + col] = f2bf(v);
                    if (C8) {
                        int pk = __builtin_amdgcn_cvt_pk_fp8_f32(v, v, 0, false);
                        C8[(size_t)row * 256 + col] = (unsigned char)(pk & 0xff);
                    }
                }
            }
        }
    }
}

// ---------- classifier head ------------------------------------------------
__global__ void cls_kernel(const unsigned short* __restrict__ h2,
                           const int* __restrict__ aidx,
                           const void* __restrict__ Wc,
                           const void* __restrict__ bc,
                           const int* __restrict__ flagp,
                           void* __restrict__ out) {
    int lin = blockIdx.x * blockDim.x + threadIdx.x;
    int a = lin >> 6, lane = lin & 63;
    if (a >= N_ASPECTS) return;
    int bf = *flagp;
    int node = aidx[a];
    uint2 v = *reinterpret_cast<const uint2*>(h2 + (size_t)node * 256 + lane * 4);
    float hv[4] = {bflo(v.x), bfhi(v.x), bflo(v.y), bfhi(v.y)};
    float a0 = 0.f, a1 = 0.f, a2 = 0.f;
#pragma unroll
    for (int r = 0; r < 4; r++) {
        int k = lane * 4 + r;
        float w0 = bf ? bf2f(((const unsigned short*)Wc)[k * 3 + 0]) : ((const float*)Wc)[k * 3 + 0];
        float w1 = bf ? bf2f(((const unsigned short*)Wc)[k * 3 + 1]) : ((const float*)Wc)[k * 3 + 1];
        float w2 = bf ? bf2f(((const unsigned short*)Wc)[k * 3 + 2]) : ((const float*)Wc)[k * 3 + 2];
        a0 += hv[r] * w0;
        a1 += hv[r] * w1;
        a2 += hv[r] * w2;
    }
#pragma unroll
    for (int off = 32; off >= 1; off >>= 1) {
        a0 += __shfl_down(a0, off);
        a1 += __shfl_down(a1, off);
        a2 += __shfl_down(a2, off);
    }
    if (lane == 0) {
        float b0 = bf ? bf2f(((const unsigned short*)bc)[0]) : ((const float*)bc)[0];
        float b1 = bf ? bf2f(((const unsigned short*)bc)[1]) : ((const float*)bc)[1];
        float b2 = bf ? bf2f(((const unsigned short*)bc)[2]) : ((const float*)bc)[2];
        if (bf) {
            unsigned short* o = (unsigned short*)out;
            o[a * 3 + 0] = f2bf(a0 + b0);
            o[a * 3 + 1] = f2bf(a1 + b1);
            o[a * 3 + 2] = f2bf(a2 + b2);
        } else {
            float* o = (float*)out;
            o[a * 3 + 0] = a0 + b0;
            o[a * 3 + 1] = a1 + b1;
            o[a * 3 + 2] = a2 + b2;
        }
    }
}

extern "C" void kernel_launch(void* const* d_in, const int* in_sizes, int n_in,
                              void* d_out, int out_size, void* d_ws, size_t ws_size,
                              hipStream_t stream) {
    const void* x   = d_in[0];
    const void* Wt1 = d_in[1];
    const void* Ws1 = d_in[2];
    const void* b1  = d_in[3];
    const void* Wt2 = d_in[4];
    const void* Ws2 = d_in[5];
    const void* b2  = d_in[6];
    const void* Wc  = d_in[7];
    const void* bc  = d_in[8];
    const int* ei = (const int*)d_in[9];
    const int* et = (const int*)d_in[10];
    const int* ai = (const int*)d_in[11];

    char* ws = (char*)d_ws;
    size_t off = 0;
    auto alloc = [&](size_t bytes) {
        void* p = ws + off;
        off += (bytes + 255) & ~(size_t)255;
        return p;
    };
    int*            flag          = (int*)alloc(4);
    int*            bucket_cursor = (int*)alloc((size_t)NBUCK * 4);
    int*            offsets4      = (int*)alloc((size_t)(NT4 + 1) * 4);
    unsigned int*   breg          = (unsigned int*)alloc((size_t)NBUCK * BCAP * 4); // 3.2 MB
    unsigned short* perm          = (unsigned short*)alloc((size_t)N_EDGES * 2);
    unsigned short* xc            = (unsigned short*)alloc((size_t)N_NODES * IN_DIM * 2);
    unsigned int*   xc8           = (unsigned int*)alloc((size_t)N_NODES * IN_DIM);    // 2.6 MB fp8
    unsigned short* AG            = (unsigned short*)alloc((size_t)N_NODES * 4 * HID_DIM * 2);
    unsigned short* h             = (unsigned short*)alloc((size_t)N_NODES * HID_DIM * 2);
    unsigned char*  h8            = (unsigned char*)alloc((size_t)N_NODES * HID_DIM);  // 5.1 MB fp8
    unsigned short* h2            = (unsigned short*)alloc((size_t)N_NODES * HID_DIM * 2);
    unsigned short* WT1           = (unsigned short*)alloc((size_t)640 * 256 * 2);
    unsigned short* WT2           = (unsigned short*)alloc((size_t)1280 * 256 * 2);
    // total ~60 MB

    hipMemsetAsync(bucket_cursor, 0, (size_t)NBUCK * 4, stream);
    prepA_kernel<<<3421, 256, 0, stream>>>(x, Ws1, Wt1, Ws2, Wt2, ei, et,
                                           xc, xc8, WT1, WT2, bucket_cursor, breg, flag);
    bucketB_kernel<<<NBUCK, 256, 0, stream>>>(breg, bucket_cursor, perm, offsets4);

    // Layer 1 (fp8 gather on x; self-term X stays bf16)
    agg8_kernel<IN_DIM><<<4096, 256, 0, stream>>>(xc8, offsets4, perm, AG);
    gemm_kernel<IN_DIM><<<1280, 256, 0, stream>>>(xc, AG, WT1, b1, flag, h, h8, N_NODES, 1);
    // Layer 2 (fp8 shadow emitted by gemm1's epilogue)
    agg8_kernel<HID_DIM><<<4096, 256, 0, stream>>>((const unsigned int*)h8, offsets4, perm, AG);
    gemm_kernel<HID_DIM><<<1280, 256, 0, stream>>>(h, AG, WT2, b2, flag, h2, nullptr, N_NODES, 0);
    // Head
    cls_kernel<<<(N_ASPECTS * 64) / 256, 256, 0, stream>>>(h2, ai, Wc, bc, flag, d_out);
}

// Round 8
// 226.723 us; speedup vs baseline: 3.4374x; 1.2063x over previous
//
#include <hip/hip_runtime.h>

#define N_NODES   20000
#define N_EDGES   640000
#define IN_DIM    128
#define HID_DIM   256
#define N_TYPES   4
#define N_ASPECTS 4096
#define NT4       (N_NODES * N_TYPES)   // 80000 CSR segments
#define NBUCK     157                   // dst buckets of 128 nodes
#define BCAP      5120                  // bucket capacity (mean 4096 + 16 sigma)
#define CHUNK     2560                  // edges per bucketA block (250 blocks exact)

typedef __bf16 v8bf __attribute__((ext_vector_type(8)));
typedef float  f32x4 __attribute__((ext_vector_type(4)));
typedef float  v2f   __attribute__((ext_vector_type(2)));

static __device__ __forceinline__ float bf2f(unsigned short u) {
    return __builtin_bit_cast(float, ((unsigned int)u) << 16);
}
static __device__ __forceinline__ float bflo(unsigned int u) {
    return __builtin_bit_cast(float, u << 16);
}
static __device__ __forceinline__ float bfhi(unsigned int u) {
    return __builtin_bit_cast(float, u & 0xffff0000u);
}
// f32 -> bf16 round-to-nearest-even (finite values)
static __device__ __forceinline__ unsigned short f2bf(float f) {
    unsigned int u = __builtin_bit_cast(unsigned int, f);
    u += 0x7fffu + ((u >> 16) & 1u);
    return (unsigned short)(u >> 16);
}

// Per-block dtype detection: 1 KB sample of W_self1.
static __device__ __forceinline__ int local_flag(const unsigned short* w, int* red) {
    int tid = threadIdx.x;
    int c = 0;
    for (int i = tid; i < 1024; i += 256) {
        unsigned hb = (w[i] >> 8) & 0x7f;
        c += (hb >= 0x39 && hb <= 0x3D) ? 1 : 0;
    }
#pragma unroll
    for (int off = 32; off >= 1; off >>= 1) c += __shfl_down(c, off);
    if ((tid & 63) == 0) red[tid >> 6] = c;
    __syncthreads();
    int tot = red[0] + red[1] + red[2] + red[3];
    __syncthreads();
    return (tot >= 768) ? 1 : 0;
}

// ---------- fused: bucketA | convx(+fp8) | packW1 | packW2 | flag ----------
__global__ __launch_bounds__(256) void prepA_kernel(
        const void* __restrict__ x,
        const void* __restrict__ Ws1, const void* __restrict__ Wt1,
        const void* __restrict__ Ws2, const void* __restrict__ Wt2,
        const int* __restrict__ ei, const int* __restrict__ et,
        unsigned short* __restrict__ xc,
        unsigned int* __restrict__ xc8,
        unsigned short* __restrict__ WT1,
        unsigned short* __restrict__ WT2,
        int* __restrict__ bucket_cursor,
        unsigned int* __restrict__ breg,
        int* __restrict__ flag) {
    __shared__ __align__(16) char smem[14336];
    int b = blockIdx.x, tid = threadIdx.x;
    if (b < 250) {
        unsigned int* ord = (unsigned int*)smem;             // 2560*4 = 10240
        int* hist  = (int*)(smem + 10240);
        int* start = hist + NBUCK;
        int* cur   = start + NBUCK;
        int* gbase = cur + NBUCK;
        int* sbuf  = gbase + NBUCK;
        int e0 = b * CHUNK;
        for (int i = tid; i < NBUCK; i += 256) hist[i] = 0;
        __syncthreads();
        unsigned int pk[10];
        int bk[10];
#pragma unroll
        for (int r = 0; r < 10; r++) {
            int e = e0 + r * 256 + tid;
            int s = __builtin_nontemporal_load(ei + e);
            int d = __builtin_nontemporal_load(ei + N_EDGES + e);
            int t = __builtin_nontemporal_load(et + e);
            pk[r] = (unsigned int)s | ((unsigned int)t << 15) | ((unsigned int)d << 17);
            bk[r] = d >> 7;
            atomicAdd(&hist[bk[r]], 1);
        }
        __syncthreads();
        int v = (tid < NBUCK) ? hist[tid] : 0;
        sbuf[tid] = v;
        __syncthreads();
        for (int o = 1; o < 256; o <<= 1) {
            int t = (tid >= o) ? sbuf[tid - o] : 0;
            __syncthreads();
            sbuf[tid] += t;
            __syncthreads();
        }
        if (tid < NBUCK) { start[tid] = sbuf[tid] - v; cur[tid] = sbuf[tid] - v; }
        __syncthreads();
#pragma unroll
        for (int r = 0; r < 10; r++) {
            int p = atomicAdd(&cur[bk[r]], 1);
            ord[p] = pk[r];
        }
        __syncthreads();
        for (int bb = tid; bb < NBUCK; bb += 256)
            if (hist[bb] > 0) gbase[bb] = atomicAdd(bucket_cursor + bb, hist[bb]);
        __syncthreads();
        for (int p = tid; p < CHUNK; p += 256) {
            unsigned int e = ord[p];
            int bb = (int)(e >> 24);
            int gp = gbase[bb] + (p - start[bb]);
            if (gp < BCAP)
                __builtin_nontemporal_store(e, breg + (size_t)bb * BCAP + gp);
        }
    } else if (b < 1500) {               // convx: bf16 copy + fp8 shadow
        int bf = local_flag((const unsigned short*)Ws1, (int*)smem);
        int idx = (b - 250) * 256 + tid;  // 8-elem chunk
        float f[8];
        if (bf) {
            uint4 v = reinterpret_cast<const uint4*>(x)[idx];
            reinterpret_cast<uint4*>(xc)[idx] = v;
            f[0] = bflo(v.x); f[1] = bfhi(v.x);
            f[2] = bflo(v.y); f[3] = bfhi(v.y);
            f[4] = bflo(v.z); f[5] = bfhi(v.z);
            f[6] = bflo(v.w); f[7] = bfhi(v.w);
        } else {
            const float* xf = reinterpret_cast<const float*>(x) + (size_t)idx * 8;
            unsigned short r[8] __attribute__((aligned(16)));
#pragma unroll
            for (int j = 0; j < 8; j++) { f[j] = xf[j]; r[j] = f2bf(xf[j]); }
            reinterpret_cast<uint4*>(xc)[idx] = *reinterpret_cast<const uint4*>(r);
        }
        int lo = 0, hi = 0;
        lo = __builtin_amdgcn_cvt_pk_fp8_f32(f[0], f[1], lo, false);
        lo = __builtin_amdgcn_cvt_pk_fp8_f32(f[2], f[3], lo, true);
        hi = __builtin_amdgcn_cvt_pk_fp8_f32(f[4], f[5], hi, false);
        hi = __builtin_amdgcn_cvt_pk_fp8_f32(f[6], f[7], hi, true);
        xc8[idx * 2]     = (unsigned int)lo;
        xc8[idx * 2 + 1] = (unsigned int)hi;
    } else if (b < 2140) {               // packW1
        int bf = local_flag((const unsigned short*)Ws1, (int*)smem);
        int idx = (b - 1500) * 256 + tid;
        int n = idx / 640, k = idx - n * 640;
        const void* p = (k < 128) ? Ws1 : Wt1;
        size_t src = (k < 128) ? ((size_t)k * 256 + n) : ((size_t)(k - 128) * 256 + n);
        WT1[idx] = bf ? ((const unsigned short*)p)[src] : f2bf(((const float*)p)[src]);
    } else if (b < 3420) {               // packW2
        int bf = local_flag((const unsigned short*)Ws1, (int*)smem);
        int idx = (b - 2140) * 256 + tid;
        int n = idx / 1280, k = idx - n * 1280;
        const void* p = (k < 256) ? Ws2 : Wt2;
        size_t src = (k < 256) ? ((size_t)k * 256 + n) : ((size_t)(k - 256) * 256 + n);
        WT2[idx] = bf ? ((const unsigned short*)p)[src] : f2bf(((const float*)p)[src]);
    } else {
        int bf = local_flag((const unsigned short*)Ws1, (int*)smem);
        if (tid == 0) *flag = bf;
    }
}

// Pass B: per-bucket counting sort -> perm + offsets4 (parallel scans).
__global__ __launch_bounds__(256) void bucketB_kernel(
        const unsigned int* __restrict__ breg,
        const int* __restrict__ bucket_cursor,
        unsigned short* __restrict__ perm,
        int* __restrict__ offsets4) {
    __shared__ int cnt[512], off[512];
    __shared__ int buf[256], pscan[256];
    int b = blockIdx.x, tid = threadIdx.x;
    int cv = (tid < NBUCK) ? bucket_cursor[tid] : 0;
    if (cv > BCAP) cv = BCAP;
    buf[tid] = cv;
    __syncthreads();
    for (int o = 1; o < 256; o <<= 1) {
        int t = (tid >= o) ? buf[tid - o] : 0;
        __syncthreads();
        buf[tid] += t;
        __syncthreads();
    }
    int obase = (b > 0) ? buf[b - 1] : 0;
    if (b == 0 && tid == 0) offsets4[NT4] = buf[255];
    int Eb = bucket_cursor[b];
    if (Eb > BCAP) Eb = BCAP;
    for (int i = tid; i < 512; i += 256) cnt[i] = 0;
    __syncthreads();
    const unsigned int* reg = breg + (size_t)b * BCAP;
    for (int i = tid; i < Eb; i += 256) {
        unsigned int e = reg[i];
        int seg = (((e >> 17) & 127) << 2) | ((e >> 15) & 3);
        atomicAdd(&cnt[seg], 1);
    }
    __syncthreads();
    int pv = cnt[2 * tid] + cnt[2 * tid + 1];
    pscan[tid] = pv;
    __syncthreads();
    for (int o = 1; o < 256; o <<= 1) {
        int t = (tid >= o) ? pscan[tid - o] : 0;
        __syncthreads();
        pscan[tid] += t;
        __syncthreads();
    }
    int pexcl = pscan[tid] - pv;
    off[2 * tid]     = pexcl;
    off[2 * tid + 1] = pexcl + cnt[2 * tid];
    __syncthreads();
    for (int i = tid; i < 512; i += 256) {
        int node = b * 128 + (i >> 2);
        if (node < N_NODES) offsets4[node * 4 + (i & 3)] = obase + off[i];
    }
    __syncthreads();
    for (int i = tid; i < Eb; i += 256) {
        unsigned int e = reg[i];
        int seg = (((e >> 17) & 127) << 2) | ((e >> 15) & 3);
        int p = atomicAdd(&off[seg], 1);
        perm[obase + p] = (unsigned short)(e & 0x7fff);
    }
}

// ---------- typed aggregation: fp8 gather, f32 accumulate ------------------
// R23: unified masked-ILP4 loop (uint2, 8B/lane). EVERY round keeps 4
// loads in flight per lane; invalid slots clamp to edge m-1 and are
// zero-masked (fp8 0x00 == +0.0). Replaces R0's main+serial-tail: with
// avg segment m~8, ~45% of segments previously ran the 1-load-in-flight
// tail (up to 4 sequential ~600cy LLC rounds) — the dominant latency.
static __device__ __forceinline__ void acc8(uint2 x, float* a) {
    v2f p0 = __builtin_amdgcn_cvt_pk_f32_fp8((int)x.x, false);
    v2f p1 = __builtin_amdgcn_cvt_pk_f32_fp8((int)x.x, true);
    v2f p2 = __builtin_amdgcn_cvt_pk_f32_fp8((int)x.y, false);
    v2f p3 = __builtin_amdgcn_cvt_pk_f32_fp8((int)x.y, true);
    a[0] += p0.x; a[1] += p0.y;
    a[2] += p1.x; a[3] += p1.y;
    a[4] += p2.x; a[5] += p2.y;
    a[6] += p3.x; a[7] += p3.y;
}

template <int D>
__global__ __launch_bounds__(256) void agg8_kernel(
        const unsigned int* __restrict__ F8,     // [N, D] fp8 (uint-chunked)
        const int* __restrict__ offs4,
        const unsigned short* __restrict__ perm,
        unsigned short* __restrict__ AG) {       // [N, 4*D] bf16
    constexpr int G = D / 8;                     // 16 (D=128) or 32 (D=256)
    constexpr int NSUB = 64 / G;                 // 4 or 2
    int wave = threadIdx.x >> 6, lane = threadIdx.x & 63;
    int sg = lane / G;
    int gl = lane - sg * G;
    for (int n = blockIdx.x * 4 + wave; n < N_NODES; n += gridDim.x * 4) {
        int o0 = offs4[n * 4];
        int o4 = offs4[n * 4 + 4];
        int deg = o4 - o0;
        float inv = 1.0f / (float)(deg > 1 ? deg : 1);
        int s0 = o0;
#pragma unroll
        for (int t = 0; t < 4; t++) {
            int s1 = offs4[n * 4 + t + 1];
            float a[8];
#pragma unroll
            for (int v = 0; v < 8; v++) a[v] = 0.f;
            int j = s0;
            while (j < s1) {
                int m = s1 - j;
                if (m > 64) m = 64;
                int pw = (int)perm[j + ((lane < m) ? lane : 0)];
                for (int k = 0; k < m; k += NSUB * 4) {
                    uint2 x[4];
#pragma unroll
                    for (int l = 0; l < 4; l++) {
                        int idx   = k + sg * 4 + l;
                        int valid = (idx < m);
                        int src   = __shfl(pw, valid ? idx : (m - 1));
                        x[l] = *reinterpret_cast<const uint2*>(F8 + (size_t)src * (D / 4) + gl * 2);
                        unsigned msk = valid ? 0xffffffffu : 0u;
                        x[l].x &= msk; x[l].y &= msk;
                    }
#pragma unroll
                    for (int l = 0; l < 4; l++) acc8(x[l], a);
                }
                j += m;
            }
#pragma unroll
            for (int v = 0; v < 8; v++) {
                float s = a[v];
                s += __shfl_xor(s, G);
                if (NSUB == 4) s += __shfl_xor(s, 2 * G);
                a[v] = s * inv;
            }
            if (sg == 0) {
                unsigned short r[8] __attribute__((aligned(16)));
#pragma unroll
                for (int v = 0; v < 8; v++) r[v] = f2bf(a[v]);
                *reinterpret_cast<uint4*>(AG + (size_t)n * (4 * D) + t * D + gl * 8) =
                    *reinterpret_cast<const uint4*>(r);
            }
            s0 = s1;
        }
    }
}

// ---------- MFMA GEMM: C[M,256] = [X | AG] @ WT^T + bias -------------------
// R0 structure (best measured): 64x64 tile, XCD swizzle, LDW=72 padded LDS,
// grid 1280. Optional fp8 shadow emission of C (post-activation).
template <int D>
__global__ __launch_bounds__(256, 6) void gemm_kernel(
        const unsigned short* __restrict__ X,
        const unsigned short* __restrict__ AG,
        const unsigned short* __restrict__ BT,
        const void* __restrict__ bias,
        const int* __restrict__ flagp,
        unsigned short* __restrict__ C,
        unsigned char* __restrict__ C8,          // fp8 shadow (or nullptr)
        int M, int relu) {
    constexpr int K = 5 * D;
    constexpr int LDW = 72;
    __shared__ __align__(16) unsigned short As[64 * LDW];
    __shared__ __align__(16) unsigned short Bs[64 * LDW];
    int b = blockIdx.x;
    int mt = (b & 7) + 8 * (b >> 5);
    int nt = (b >> 3) & 3;
    int mtiles = (M + 63) >> 6;
    if (mt >= mtiles) return;
    int m0 = mt * 64;
    int n0 = nt * 64;
    int tid  = threadIdx.x;
    int wave = tid >> 6, lane = tid & 63;
    int wm = wave >> 1, wn = wave & 1;
    int quad = lane >> 4, l16 = lane & 15;

    f32x4 acc[2][2];
#pragma unroll
    for (int i = 0; i < 2; i++)
#pragma unroll
        for (int j = 0; j < 2; j++) acc[i][j] = (f32x4){0.f, 0.f, 0.f, 0.f};

    for (int k0 = 0; k0 < K; k0 += 64) {
        const unsigned short* base = (k0 < D) ? X : AG;
        int rs  = (k0 < D) ? D : 4 * D;
        int col = (k0 < D) ? k0 : (k0 - D);
#pragma unroll
        for (int cc = 0; cc < 2; cc++) {
            int c   = tid + cc * 256;
            int row = c >> 3;
            int c8  = c & 7;
            uint4 va = make_uint4(0u, 0u, 0u, 0u);
            int gr = m0 + row;
            if (gr < M)
                va = *reinterpret_cast<const uint4*>(base + (size_t)gr * rs + col + c8 * 8);
            *reinterpret_cast<uint4*>(&As[row * LDW + c8 * 8]) = va;
            uint4 vb = *reinterpret_cast<const uint4*>(BT + (size_t)(n0 + row) * K + k0 + c8 * 8);
            *reinterpret_cast<uint4*>(&Bs[row * LDW + c8 * 8]) = vb;
        }
        __syncthreads();
#pragma unroll
        for (int ks = 0; ks < 2; ks++) {
            v8bf af[2], bfr[2];
#pragma unroll
            for (int i = 0; i < 2; i++)
                af[i] = *reinterpret_cast<const v8bf*>(
                    &As[(wm * 32 + i * 16 + l16) * LDW + ks * 32 + quad * 8]);
#pragma unroll
            for (int j = 0; j < 2; j++)
                bfr[j] = *reinterpret_cast<const v8bf*>(
                    &Bs[(wn * 32 + j * 16 + l16) * LDW + ks * 32 + quad * 8]);
#pragma unroll
            for (int i = 0; i < 2; i++)
#pragma unroll
                for (int j = 0; j < 2; j++)
                    acc[i][j] = __builtin_amdgcn_mfma_f32_16x16x32_bf16(af[i], bfr[j], acc[i][j], 0, 0, 0);
        }
        __syncthreads();
    }
    int bf = *flagp;
#pragma unroll
    for (int i = 0; i < 2; i++) {
#pragma unroll
        for (int j = 0; j < 2; j++) {
            int col = n0 + wn * 32 + j * 16 + l16;
            float bv = bf ? bf2f(((const unsigned short*)bias)[col])
                          : ((const float*)bias)[col];
#pragma unroll
            for (int r = 0; r < 4; r++) {
                int row = m0 + wm * 32 + i * 16 + quad * 4 + r;
                if (row < M) {
                    float v = acc[i][j][r] + bv;
                    if (relu) v = fmaxf(v, 0.0f);
                    C[(size_t)row * 256 + col] = f2bf(v);
                    if (C8) {
                        int pk = __builtin_amdgcn_cvt_pk_fp8_f32(v, v, 0, false);
                        C8[(size_t)row * 256 + col] = (unsigned char)(pk & 0xff);
                    }
                }
            }
        }
    }
}

// ---------- classifier head ------------------------------------------------
__global__ void cls_kernel(const unsigned short* __restrict__ h2,
                           const int* __restrict__ aidx,
                           const void* __restrict__ Wc,
                           const void* __restrict__ bc,
                           const int* __restrict__ flagp,
                           void* __restrict__ out) {
    int lin = blockIdx.x * blockDim.x + threadIdx.x;
    int a = lin >> 6, lane = lin & 63;
    if (a >= N_ASPECTS) return;
    int bf = *flagp;
    int node = aidx[a];
    uint2 v = *reinterpret_cast<const uint2*>(h2 + (size_t)node * 256 + lane * 4);
    float hv[4] = {bflo(v.x), bfhi(v.x), bflo(v.y), bfhi(v.y)};
    float a0 = 0.f, a1 = 0.f, a2 = 0.f;
#pragma unroll
    for (int r = 0; r < 4; r++) {
        int k = lane * 4 + r;
        float w0 = bf ? bf2f(((const unsigned short*)Wc)[k * 3 + 0]) : ((const float*)Wc)[k * 3 + 0];
        float w1 = bf ? bf2f(((const unsigned short*)Wc)[k * 3 + 1]) : ((const float*)Wc)[k * 3 + 1];
        float w2 = bf ? bf2f(((const unsigned short*)Wc)[k * 3 + 2]) : ((const float*)Wc)[k * 3 + 2];
        a0 += hv[r] * w0;
        a1 += hv[r] * w1;
        a2 += hv[r] * w2;
    }
#pragma unroll
    for (int off = 32; off >= 1; off >>= 1) {
        a0 += __shfl_down(a0, off);
        a1 += __shfl_down(a1, off);
        a2 += __shfl_down(a2, off);
    }
    if (lane == 0) {
        float b0 = bf ? bf2f(((const unsigned short*)bc)[0]) : ((const float*)bc)[0];
        float b1 = bf ? bf2f(((const unsigned short*)bc)[1]) : ((const float*)bc)[1];
        float b2 = bf ? bf2f(((const unsigned short*)bc)[2]) : ((const float*)bc)[2];
        if (bf) {
            unsigned short* o = (unsigned short*)out;
            o[a * 3 + 0] = f2bf(a0 + b0);
            o[a * 3 + 1] = f2bf(a1 + b1);
            o[a * 3 + 2] = f2bf(a2 + b2);
        } else {
            float* o = (float*)out;
            o[a * 3 + 0] = a0 + b0;
            o[a * 3 + 1] = a1 + b1;
            o[a * 3 + 2] = a2 + b2;
        }
    }
}

extern "C" void kernel_launch(void* const* d_in, const int* in_sizes, int n_in,
                              void* d_out, int out_size, void* d_ws, size_t ws_size,
                              hipStream_t stream) {
    const void* x   = d_in[0];
    const void* Wt1 = d_in[1];
    const void* Ws1 = d_in[2];
    const void* b1  = d_in[3];
    const void* Wt2 = d_in[4];
    const void* Ws2 = d_in[5];
    const void* b2  = d_in[6];
    const void* Wc  = d_in[7];
    const void* bc  = d_in[8];
    const int* ei = (const int*)d_in[9];
    const int* et = (const int*)d_in[10];
    const int* ai = (const int*)d_in[11];

    char* ws = (char*)d_ws;
    size_t off = 0;
    auto alloc = [&](size_t bytes) {
        void* p = ws + off;
        off += (bytes + 255) & ~(size_t)255;
        return p;
    };
    int*            flag          = (int*)alloc(4);
    int*            bucket_cursor = (int*)alloc((size_t)NBUCK * 4);
    int*            offsets4      = (int*)alloc((size_t)(NT4 + 1) * 4);
    unsigned int*   breg          = (unsigned int*)alloc((size_t)NBUCK * BCAP * 4); // 3.2 MB
    unsigned short* perm          = (unsigned short*)alloc((size_t)N_EDGES * 2);
    unsigned short* xc            = (unsigned short*)alloc((size_t)N_NODES * IN_DIM * 2);
    unsigned int*   xc8           = (unsigned int*)alloc((size_t)N_NODES * IN_DIM);    // 2.6 MB fp8
    unsigned short* AG            = (unsigned short*)alloc((size_t)N_NODES * 4 * HID_DIM * 2);
    unsigned short* h             = (unsigned short*)alloc((size_t)N_NODES * HID_DIM * 2);
    unsigned char*  h8            = (unsigned char*)alloc((size_t)N_NODES * HID_DIM);  // 5.1 MB fp8
    unsigned short* h2            = (unsigned short*)alloc((size_t)N_NODES * HID_DIM * 2);
    unsigned short* WT1           = (unsigned short*)alloc((size_t)640 * 256 * 2);
    unsigned short* WT2           = (unsigned short*)alloc((size_t)1280 * 256 * 2);
    // total ~60 MB

    hipMemsetAsync(bucket_cursor, 0, (size_t)NBUCK * 4, stream);
    prepA_kernel<<<3421, 256, 0, stream>>>(x, Ws1, Wt1, Ws2, Wt2, ei, et,
                                           xc, xc8, WT1, WT2, bucket_cursor, breg, flag);
    bucketB_kernel<<<NBUCK, 256, 0, stream>>>(breg, bucket_cursor, perm, offsets4);

    // Layer 1 (fp8 gather on x; self-term X stays bf16)
    agg8_kernel<IN_DIM><<<4096, 256, 0, stream>>>(xc8, offsets4, perm, AG);
    gemm_kernel<IN_DIM><<<1280, 256, 0, stream>>>(xc, AG, WT1, b1, flag, h, h8, N_NODES, 1);
    // Layer 2 (fp8 shadow emitted by gemm1's epilogue)
    agg8_kernel<HID_DIM><<<4096, 256, 0, stream>>>((const unsigned int*)h8, offsets4, perm, AG);
    gemm_kernel<HID_DIM><<<1280, 256, 0, stream>>>(h, AG, WT2, b2, flag, h2, nullptr, N_NODES, 0);
    // Head
    cls_kernel<<<(N_ASPECTS * 64) / 256, 256, 0, stream>>>(h2, ai, Wc, bc, flag, d_out);
}

// Round 9
// 218.980 us; speedup vs baseline: 3.5589x; 1.0354x over previous
//
#include <hip/hip_runtime.h>

#define N_NODES   20000
#define N_EDGES   640000
#define IN_DIM    128
#define HID_DIM   256
#define N_TYPES   4
#define N_ASPECTS 4096
#define NT4       (N_NODES * N_TYPES)   // 80000 CSR segments
#define NBUCK     157                   // dst buckets of 128 nodes
#define BCAP      5120                  // bucket capacity (mean 4096 + 16 sigma)
#define CHUNK     2560                  // edges per bucketA block (250 blocks exact)

typedef __bf16 v8bf __attribute__((ext_vector_type(8)));
typedef float  f32x4 __attribute__((ext_vector_type(4)));
typedef float  v2f   __attribute__((ext_vector_type(2)));

static __device__ __forceinline__ float bf2f(unsigned short u) {
    return __builtin_bit_cast(float, ((unsigned int)u) << 16);
}
static __device__ __forceinline__ float bflo(unsigned int u) {
    return __builtin_bit_cast(float, u << 16);
}
static __device__ __forceinline__ float bfhi(unsigned int u) {
    return __builtin_bit_cast(float, u & 0xffff0000u);
}
// f32 -> bf16 round-to-nearest-even (finite values)
static __device__ __forceinline__ unsigned short f2bf(float f) {
    unsigned int u = __builtin_bit_cast(unsigned int, f);
    u += 0x7fffu + ((u >> 16) & 1u);
    return (unsigned short)(u >> 16);
}

// Per-block dtype detection: 1 KB sample of W_self1.
static __device__ __forceinline__ int local_flag(const unsigned short* w, int* red) {
    int tid = threadIdx.x;
    int c = 0;
    for (int i = tid; i < 1024; i += 256) {
        unsigned hb = (w[i] >> 8) & 0x7f;
        c += (hb >= 0x39 && hb <= 0x3D) ? 1 : 0;
    }
#pragma unroll
    for (int off = 32; off >= 1; off >>= 1) c += __shfl_down(c, off);
    if ((tid & 63) == 0) red[tid >> 6] = c;
    __syncthreads();
    int tot = red[0] + red[1] + red[2] + red[3];
    __syncthreads();
    return (tot >= 768) ? 1 : 0;
}

// ---------- fused: bucketA | convx(+fp8) | packW1 | packW2 | flag ----------
__global__ __launch_bounds__(256) void prepA_kernel(
        const void* __restrict__ x,
        const void* __restrict__ Ws1, const void* __restrict__ Wt1,
        const void* __restrict__ Ws2, const void* __restrict__ Wt2,
        const int* __restrict__ ei, const int* __restrict__ et,
        unsigned short* __restrict__ xc,
        unsigned int* __restrict__ xc8,
        unsigned short* __restrict__ WT1,
        unsigned short* __restrict__ WT2,
        int* __restrict__ bucket_cursor,
        unsigned int* __restrict__ breg,
        int* __restrict__ flag) {
    __shared__ __align__(16) char smem[14336];
    int b = blockIdx.x, tid = threadIdx.x;
    if (b < 250) {
        unsigned int* ord = (unsigned int*)smem;             // 2560*4 = 10240
        int* hist  = (int*)(smem + 10240);
        int* start = hist + NBUCK;
        int* cur   = start + NBUCK;
        int* gbase = cur + NBUCK;
        int* sbuf  = gbase + NBUCK;
        int e0 = b * CHUNK;
        for (int i = tid; i < NBUCK; i += 256) hist[i] = 0;
        __syncthreads();
        unsigned int pk[10];
        int bk[10];
#pragma unroll
        for (int r = 0; r < 10; r++) {
            int e = e0 + r * 256 + tid;
            int s = __builtin_nontemporal_load(ei + e);
            int d = __builtin_nontemporal_load(ei + N_EDGES + e);
            int t = __builtin_nontemporal_load(et + e);
            pk[r] = (unsigned int)s | ((unsigned int)t << 15) | ((unsigned int)d << 17);
            bk[r] = d >> 7;
            atomicAdd(&hist[bk[r]], 1);
        }
        __syncthreads();
        int v = (tid < NBUCK) ? hist[tid] : 0;
        sbuf[tid] = v;
        __syncthreads();
        for (int o = 1; o < 256; o <<= 1) {
            int t = (tid >= o) ? sbuf[tid - o] : 0;
            __syncthreads();
            sbuf[tid] += t;
            __syncthreads();
        }
        if (tid < NBUCK) { start[tid] = sbuf[tid] - v; cur[tid] = sbuf[tid] - v; }
        __syncthreads();
#pragma unroll
        for (int r = 0; r < 10; r++) {
            int p = atomicAdd(&cur[bk[r]], 1);
            ord[p] = pk[r];
        }
        __syncthreads();
        for (int bb = tid; bb < NBUCK; bb += 256)
            if (hist[bb] > 0) gbase[bb] = atomicAdd(bucket_cursor + bb, hist[bb]);
        __syncthreads();
        for (int p = tid; p < CHUNK; p += 256) {
            unsigned int e = ord[p];
            int bb = (int)(e >> 24);
            int gp = gbase[bb] + (p - start[bb]);
            if (gp < BCAP)
                __builtin_nontemporal_store(e, breg + (size_t)bb * BCAP + gp);
        }
    } else if (b < 1500) {               // convx: bf16 copy + fp8 shadow
        int bf = local_flag((const unsigned short*)Ws1, (int*)smem);
        int idx = (b - 250) * 256 + tid;  // 8-elem chunk
        float f[8];
        if (bf) {
            uint4 v = reinterpret_cast<const uint4*>(x)[idx];
            reinterpret_cast<uint4*>(xc)[idx] = v;
            f[0] = bflo(v.x); f[1] = bfhi(v.x);
            f[2] = bflo(v.y); f[3] = bfhi(v.y);
            f[4] = bflo(v.z); f[5] = bfhi(v.z);
            f[6] = bflo(v.w); f[7] = bfhi(v.w);
        } else {
            const float* xf = reinterpret_cast<const float*>(x) + (size_t)idx * 8;
            unsigned short r[8] __attribute__((aligned(16)));
#pragma unroll
            for (int j = 0; j < 8; j++) { f[j] = xf[j]; r[j] = f2bf(xf[j]); }
            reinterpret_cast<uint4*>(xc)[idx] = *reinterpret_cast<const uint4*>(r);
        }
        int lo = 0, hi = 0;
        lo = __builtin_amdgcn_cvt_pk_fp8_f32(f[0], f[1], lo, false);
        lo = __builtin_amdgcn_cvt_pk_fp8_f32(f[2], f[3], lo, true);
        hi = __builtin_amdgcn_cvt_pk_fp8_f32(f[4], f[5], hi, false);
        hi = __builtin_amdgcn_cvt_pk_fp8_f32(f[6], f[7], hi, true);
        xc8[idx * 2]     = (unsigned int)lo;
        xc8[idx * 2 + 1] = (unsigned int)hi;
    } else if (b < 2140) {               // packW1
        int bf = local_flag((const unsigned short*)Ws1, (int*)smem);
        int idx = (b - 1500) * 256 + tid;
        int n = idx / 640, k = idx - n * 640;
        const void* p = (k < 128) ? Ws1 : Wt1;
        size_t src = (k < 128) ? ((size_t)k * 256 + n) : ((size_t)(k - 128) * 256 + n);
        WT1[idx] = bf ? ((const unsigned short*)p)[src] : f2bf(((const float*)p)[src]);
    } else if (b < 3420) {               // packW2
        int bf = local_flag((const unsigned short*)Ws1, (int*)smem);
        int idx = (b - 2140) * 256 + tid;
        int n = idx / 1280, k = idx - n * 1280;
        const void* p = (k < 256) ? Ws2 : Wt2;
        size_t src = (k < 256) ? ((size_t)k * 256 + n) : ((size_t)(k - 256) * 256 + n);
        WT2[idx] = bf ? ((const unsigned short*)p)[src] : f2bf(((const float*)p)[src]);
    } else {
        int bf = local_flag((const unsigned short*)Ws1, (int*)smem);
        if (tid == 0) *flag = bf;
    }
}

// Pass B: per-bucket counting sort -> perm + offsets4 (parallel scans).
__global__ __launch_bounds__(256) void bucketB_kernel(
        const unsigned int* __restrict__ breg,
        const int* __restrict__ bucket_cursor,
        unsigned short* __restrict__ perm,
        int* __restrict__ offsets4) {
    __shared__ int cnt[512], off[512];
    __shared__ int buf[256], pscan[256];
    int b = blockIdx.x, tid = threadIdx.x;
    int cv = (tid < NBUCK) ? bucket_cursor[tid] : 0;
    if (cv > BCAP) cv = BCAP;
    buf[tid] = cv;
    __syncthreads();
    for (int o = 1; o < 256; o <<= 1) {
        int t = (tid >= o) ? buf[tid - o] : 0;
        __syncthreads();
        buf[tid] += t;
        __syncthreads();
    }
    int obase = (b > 0) ? buf[b - 1] : 0;
    if (b == 0 && tid == 0) offsets4[NT4] = buf[255];
    int Eb = bucket_cursor[b];
    if (Eb > BCAP) Eb = BCAP;
    for (int i = tid; i < 512; i += 256) cnt[i] = 0;
    __syncthreads();
    const unsigned int* reg = breg + (size_t)b * BCAP;
    for (int i = tid; i < Eb; i += 256) {
        unsigned int e = reg[i];
        int seg = (((e >> 17) & 127) << 2) | ((e >> 15) & 3);
        atomicAdd(&cnt[seg], 1);
    }
    __syncthreads();
    int pv = cnt[2 * tid] + cnt[2 * tid + 1];
    pscan[tid] = pv;
    __syncthreads();
    for (int o = 1; o < 256; o <<= 1) {
        int t = (tid >= o) ? pscan[tid - o] : 0;
        __syncthreads();
        pscan[tid] += t;
        __syncthreads();
    }
    int pexcl = pscan[tid] - pv;
    off[2 * tid]     = pexcl;
    off[2 * tid + 1] = pexcl + cnt[2 * tid];
    __syncthreads();
    for (int i = tid; i < 512; i += 256) {
        int node = b * 128 + (i >> 2);
        if (node < N_NODES) offsets4[node * 4 + (i & 3)] = obase + off[i];
    }
    __syncthreads();
    for (int i = tid; i < Eb; i += 256) {
        unsigned int e = reg[i];
        int seg = (((e >> 17) & 127) << 2) | ((e >> 15) & 3);
        int p = atomicAdd(&off[seg], 1);
        perm[obase + p] = (unsigned short)(e & 0x7fff);
    }
}

// ---------- typed aggregation: fp8 gather, f32 accumulate ------------------
// R24: one node per G-lane subgroup (G = D/8: 32 or 16) + masked ILP8.
// Each subgroup owns a full node: its lanes hold 8 output dims each, so
// there is NO cross-subgroup reduce; every round issues 8 independent
// edge loads (invalid slots clamp to edge m-1, zero-masked — fp8 0x00 ==
// +0.0). Per-wave loads in flight: 16 (D=256) / 32 (D=128), 2-4
// independent latency chains per wave (R23 had 8 in flight, 1 chain).
// perm broadcast stays in-subgroup via __shfl(.., width=G).
static __device__ __forceinline__ void acc8(uint2 x, float* a) {
    v2f p0 = __builtin_amdgcn_cvt_pk_f32_fp8((int)x.x, false);
    v2f p1 = __builtin_amdgcn_cvt_pk_f32_fp8((int)x.x, true);
    v2f p2 = __builtin_amdgcn_cvt_pk_f32_fp8((int)x.y, false);
    v2f p3 = __builtin_amdgcn_cvt_pk_f32_fp8((int)x.y, true);
    a[0] += p0.x; a[1] += p0.y;
    a[2] += p1.x; a[3] += p1.y;
    a[4] += p2.x; a[5] += p2.y;
    a[6] += p3.x; a[7] += p3.y;
}

template <int D>
__global__ __launch_bounds__(256) void agg8_kernel(
        const unsigned int* __restrict__ F8,     // [N, D] fp8 (uint-chunked)
        const int* __restrict__ offs4,
        const unsigned short* __restrict__ perm,
        unsigned short* __restrict__ AG) {       // [N, 4*D] bf16
    constexpr int G = D / 8;                     // 16 (D=128) or 32 (D=256)
    constexpr int SGN = 64 / G;                  // 4 or 2 subgroups (nodes)/wave
    int wave = threadIdx.x >> 6, lane = threadIdx.x & 63;
    int sg = lane / G;
    int gl = lane - sg * G;
    int sgid0   = (blockIdx.x * 4 + wave) * SGN + sg;
    int sstride = gridDim.x * 4 * SGN;
    for (int n = sgid0; n < N_NODES; n += sstride) {
        int o0 = offs4[n * 4];
        int o4 = offs4[n * 4 + 4];
        int deg = o4 - o0;
        float inv = 1.0f / (float)(deg > 1 ? deg : 1);
        int s0 = o0;
#pragma unroll
        for (int t = 0; t < 4; t++) {
            int s1 = offs4[n * 4 + t + 1];
            float a[8];
#pragma unroll
            for (int v = 0; v < 8; v++) a[v] = 0.f;
            int j = s0;
            while (j < s1) {
                int m = s1 - j;
                if (m > G) m = G;                // window = G edges
                int pw = (int)perm[j + ((gl < m) ? gl : 0)];
                for (int k = 0; k < m; k += 8) { // masked ILP8
                    uint2 x[8];
#pragma unroll
                    for (int l = 0; l < 8; l++) {
                        int idx   = k + l;
                        int valid = (idx < m);
                        int src   = __shfl(pw, valid ? idx : (m - 1), G);
                        x[l] = *reinterpret_cast<const uint2*>(F8 + (size_t)src * (D / 4) + gl * 2);
                        unsigned msk = valid ? 0xffffffffu : 0u;
                        x[l].x &= msk; x[l].y &= msk;
                    }
#pragma unroll
                    for (int l = 0; l < 8; l++) acc8(x[l], a);
                }
                j += m;
            }
            unsigned short r[8] __attribute__((aligned(16)));
#pragma unroll
            for (int v = 0; v < 8; v++) r[v] = f2bf(a[v] * inv);
            *reinterpret_cast<uint4*>(AG + (size_t)n * (4 * D) + t * D + gl * 8) =
                *reinterpret_cast<const uint4*>(r);
            s0 = s1;
        }
    }
}

// ---------- MFMA GEMM: C[M,256] = [X | AG] @ WT^T + bias -------------------
// R0 structure (best measured): 64x64 tile, XCD swizzle, LDW=72 padded LDS,
// grid 1280. Optional fp8 shadow emission of C (post-activation).
template <int D>
__global__ __launch_bounds__(256, 6) void gemm_kernel(
        const unsigned short* __restrict__ X,
        const unsigned short* __restrict__ AG,
        const unsigned short* __restrict__ BT,
        const void* __restrict__ bias,
        const int* __restrict__ flagp,
        unsigned short* __restrict__ C,
        unsigned char* __restrict__ C8,          // fp8 shadow (or nullptr)
        int M, int relu) {
    constexpr int K = 5 * D;
    constexpr int LDW = 72;
    __shared__ __align__(16) unsigned short As[64 * LDW];
    __shared__ __align__(16) unsigned short Bs[64 * LDW];
    int b = blockIdx.x;
    int mt = (b & 7) + 8 * (b >> 5);
    int nt = (b >> 3) & 3;
    int mtiles = (M + 63) >> 6;
    if (mt >= mtiles) return;
    int m0 = mt * 64;
    int n0 = nt * 64;
    int tid  = threadIdx.x;
    int wave = tid >> 6, lane = tid & 63;
    int wm = wave >> 1, wn = wave & 1;
    int quad = lane >> 4, l16 = lane & 15;

    f32x4 acc[2][2];
#pragma unroll
    for (int i = 0; i < 2; i++)
#pragma unroll
        for (int j = 0; j < 2; j++) acc[i][j] = (f32x4){0.f, 0.f, 0.f, 0.f};

    for (int k0 = 0; k0 < K; k0 += 64) {
        const unsigned short* base = (k0 < D) ? X : AG;
        int rs  = (k0 < D) ? D : 4 * D;
        int col = (k0 < D) ? k0 : (k0 - D);
#pragma unroll
        for (int cc = 0; cc < 2; cc++) {
            int c   = tid + cc * 256;
            int row = c >> 3;
            int c8  = c & 7;
            uint4 va = make_uint4(0u, 0u, 0u, 0u);
            int gr = m0 + row;
            if (gr < M)
                va = *reinterpret_cast<const uint4*>(base + (size_t)gr * rs + col + c8 * 8);
            *reinterpret_cast<uint4*>(&As[row * LDW + c8 * 8]) = va;
            uint4 vb = *reinterpret_cast<const uint4*>(BT + (size_t)(n0 + row) * K + k0 + c8 * 8);
            *reinterpret_cast<uint4*>(&Bs[row * LDW + c8 * 8]) = vb;
        }
        __syncthreads();
#pragma unroll
        for (int ks = 0; ks < 2; ks++) {
            v8bf af[2], bfr[2];
#pragma unroll
            for (int i = 0; i < 2; i++)
                af[i] = *reinterpret_cast<const v8bf*>(
                    &As[(wm * 32 + i * 16 + l16) * LDW + ks * 32 + quad * 8]);
#pragma unroll
            for (int j = 0; j < 2; j++)
                bfr[j] = *reinterpret_cast<const v8bf*>(
                    &Bs[(wn * 32 + j * 16 + l16) * LDW + ks * 32 + quad * 8]);
#pragma unroll
            for (int i = 0; i < 2; i++)
#pragma unroll
                for (int j = 0; j < 2; j++)
                    acc[i][j] = __builtin_amdgcn_mfma_f32_16x16x32_bf16(af[i], bfr[j], acc[i][j], 0, 0, 0);
        }
        __syncthreads();
    }
    int bf = *flagp;
#pragma unroll
    for (int i = 0; i < 2; i++) {
#pragma unroll
        for (int j = 0; j < 2; j++) {
            int col = n0 + wn * 32 + j * 16 + l16;
            float bv = bf ? bf2f(((const unsigned short*)bias)[col])
                          : ((const float*)bias)[col];
#pragma unroll
            for (int r = 0; r < 4; r++) {
                int row = m0 + wm * 32 + i * 16 + quad * 4 + r;
                if (row < M) {
                    float v = acc[i][j][r] + bv;
                    if (relu) v = fmaxf(v, 0.0f);
                    C[(size_t)row * 256 + col] = f2bf(v);
                    if (C8) {
                        int pk = __builtin_amdgcn_cvt_pk_fp8_f32(v, v, 0, false);
                        C8[(size_t)row * 256 + col] = (unsigned char)(pk & 0xff);
                    }
                }
            }
        }
    }
}

// ---------- classifier head ------------------------------------------------
__global__ void cls_kernel(const unsigned short* __restrict__ h2,
                           const int* __restrict__ aidx,
                           const void* __restrict__ Wc,
                           const void* __restrict__ bc,
                           const int* __restrict__ flagp,
                           void* __restrict__ out) {
    int lin = blockIdx.x * blockDim.x + threadIdx.x;
    int a = lin >> 6, lane = lin & 63;
    if (a >= N_ASPECTS) return;
    int bf = *flagp;
    int node = aidx[a];
    uint2 v = *reinterpret_cast<const uint2*>(h2 + (size_t)node * 256 + lane * 4);
    float hv[4] = {bflo(v.x), bfhi(v.x), bflo(v.y), bfhi(v.y)};
    float a0 = 0.f, a1 = 0.f, a2 = 0.f;
#pragma unroll
    for (int r = 0; r < 4; r++) {
        int k = lane * 4 + r;
        float w0 = bf ? bf2f(((const unsigned short*)Wc)[k * 3 + 0]) : ((const float*)Wc)[k * 3 + 0];
        float w1 = bf ? bf2f(((const unsigned short*)Wc)[k * 3 + 1]) : ((const float*)Wc)[k * 3 + 1];
        float w2 = bf ? bf2f(((const unsigned short*)Wc)[k * 3 + 2]) : ((const float*)Wc)[k * 3 + 2];
        a0 += hv[r] * w0;
        a1 += hv[r] * w1;
        a2 += hv[r] * w2;
    }
#pragma unroll
    for (int off = 32; off >= 1; off >>= 1) {
        a0 += __shfl_down(a0, off);
        a1 += __shfl_down(a1, off);
        a2 += __shfl_down(a2, off);
    }
    if (lane == 0) {
        float b0 = bf ? bf2f(((const unsigned short*)bc)[0]) : ((const float*)bc)[0];
        float b1 = bf ? bf2f(((const unsigned short*)bc)[1]) : ((const float*)bc)[1];
        float b2 = bf ? bf2f(((const unsigned short*)bc)[2]) : ((const float*)bc)[2];
        if (bf) {
            unsigned short* o = (unsigned short*)out;
            o[a * 3 + 0] = f2bf(a0 + b0);
            o[a * 3 + 1] = f2bf(a1 + b1);
            o[a * 3 + 2] = f2bf(a2 + b2);
        } else {
            float* o = (float*)out;
            o[a * 3 + 0] = a0 + b0;
            o[a * 3 + 1] = a1 + b1;
            o[a * 3 + 2] = a2 + b2;
        }
    }
}

extern "C" void kernel_launch(void* const* d_in, const int* in_sizes, int n_in,
                              void* d_out, int out_size, void* d_ws, size_t ws_size,
                              hipStream_t stream) {
    const void* x   = d_in[0];
    const void* Wt1 = d_in[1];
    const void* Ws1 = d_in[2];
    const void* b1  = d_in[3];
    const void* Wt2 = d_in[4];
    const void* Ws2 = d_in[5];
    const void* b2  = d_in[6];
    const void* Wc  = d_in[7];
    const void* bc  = d_in[8];
    const int* ei = (const int*)d_in[9];
    const int* et = (const int*)d_in[10];
    const int* ai = (const int*)d_in[11];

    char* ws = (char*)d_ws;
    size_t off = 0;
    auto alloc = [&](size_t bytes) {
        void* p = ws + off;
        off += (bytes + 255) & ~(size_t)255;
        return p;
    };
    int*            flag          = (int*)alloc(4);
    int*            bucket_cursor = (int*)alloc((size_t)NBUCK * 4);
    int*            offsets4      = (int*)alloc((size_t)(NT4 + 1) * 4);
    unsigned int*   breg          = (unsigned int*)alloc((size_t)NBUCK * BCAP * 4); // 3.2 MB
    unsigned short* perm          = (unsigned short*)alloc((size_t)N_EDGES * 2);
    unsigned short* xc            = (unsigned short*)alloc((size_t)N_NODES * IN_DIM * 2);
    unsigned int*   xc8           = (unsigned int*)alloc((size_t)N_NODES * IN_DIM);    // 2.6 MB fp8
    unsigned short* AG            = (unsigned short*)alloc((size_t)N_NODES * 4 * HID_DIM * 2);
    unsigned short* h             = (unsigned short*)alloc((size_t)N_NODES * HID_DIM * 2);
    unsigned char*  h8            = (unsigned char*)alloc((size_t)N_NODES * HID_DIM);  // 5.1 MB fp8
    unsigned short* h2            = (unsigned short*)alloc((size_t)N_NODES * HID_DIM * 2);
    unsigned short* WT1           = (unsigned short*)alloc((size_t)640 * 256 * 2);
    unsigned short* WT2           = (unsigned short*)alloc((size_t)1280 * 256 * 2);
    // total ~60 MB

    hipMemsetAsync(bucket_cursor, 0, (size_t)NBUCK * 4, stream);
    prepA_kernel<<<3421, 256, 0, stream>>>(x, Ws1, Wt1, Ws2, Wt2, ei, et,
                                           xc, xc8, WT1, WT2, bucket_cursor, breg, flag);
    bucketB_kernel<<<NBUCK, 256, 0, stream>>>(breg, bucket_cursor, perm, offsets4);

    // Layer 1 (fp8 gather on x; self-term X stays bf16)
    agg8_kernel<IN_DIM><<<4096, 256, 0, stream>>>(xc8, offsets4, perm, AG);
    gemm_kernel<IN_DIM><<<1280, 256, 0, stream>>>(xc, AG, WT1, b1, flag, h, h8, N_NODES, 1);
    // Layer 2 (fp8 shadow emitted by gemm1's epilogue)
    agg8_kernel<HID_DIM><<<4096, 256, 0, stream>>>((const unsigned int*)h8, offsets4, perm, AG);
    gemm_kernel<HID_DIM><<<1280, 256, 0, stream>>>(h, AG, WT2, b2, flag, h2, nullptr, N_NODES, 0);
    // Head
    cls_kernel<<<(N_ASPECTS * 64) / 256, 256, 0, stream>>>(h2, ai, Wc, bc, flag, d_out);
}

// Round 10
// 215.840 us; speedup vs baseline: 3.6107x; 1.0145x over previous
//
#include <hip/hip_runtime.h>

#define N_NODES   20000
#define N_EDGES   640000
#define IN_DIM    128
#define HID_DIM   256
#define N_TYPES   4
#define N_ASPECTS 4096
#define NT4       (N_NODES * N_TYPES)   // 80000 CSR segments
#define NBUCK     157                   // dst buckets of 128 nodes
#define BCAP      5120                  // bucket capacity (mean 4096 + 16 sigma)
#define CHUNK     2560                  // edges per bucketA block (250 blocks exact)

typedef __bf16 v8bf __attribute__((ext_vector_type(8)));
typedef float  f32x4 __attribute__((ext_vector_type(4)));
typedef float  v2f   __attribute__((ext_vector_type(2)));

static __device__ __forceinline__ float bf2f(unsigned short u) {
    return __builtin_bit_cast(float, ((unsigned int)u) << 16);
}
static __device__ __forceinline__ float bflo(unsigned int u) {
    return __builtin_bit_cast(float, u << 16);
}
static __device__ __forceinline__ float bfhi(unsigned int u) {
    return __builtin_bit_cast(float, u & 0xffff0000u);
}
// f32 -> bf16 round-to-nearest-even (finite values)
static __device__ __forceinline__ unsigned short f2bf(float f) {
    unsigned int u = __builtin_bit_cast(unsigned int, f);
    u += 0x7fffu + ((u >> 16) & 1u);
    return (unsigned short)(u >> 16);
}

// Per-block dtype detection: 1 KB sample of W_self1.
static __device__ __forceinline__ int local_flag(const unsigned short* w, int* red) {
    int tid = threadIdx.x;
    int c = 0;
    for (int i = tid; i < 1024; i += 256) {
        unsigned hb = (w[i] >> 8) & 0x7f;
        c += (hb >= 0x39 && hb <= 0x3D) ? 1 : 0;
    }
#pragma unroll
    for (int off = 32; off >= 1; off >>= 1) c += __shfl_down(c, off);
    if ((tid & 63) == 0) red[tid >> 6] = c;
    __syncthreads();
    int tot = red[0] + red[1] + red[2] + red[3];
    __syncthreads();
    return (tot >= 768) ? 1 : 0;
}

// ---------- fused: bucketA | convx(+fp8) | packW1 | packW2 | flag ----------
__global__ __launch_bounds__(256) void prepA_kernel(
        const void* __restrict__ x,
        const void* __restrict__ Ws1, const void* __restrict__ Wt1,
        const void* __restrict__ Ws2, const void* __restrict__ Wt2,
        const int* __restrict__ ei, const int* __restrict__ et,
        unsigned short* __restrict__ xc,
        unsigned int* __restrict__ xc8,
        unsigned short* __restrict__ WT1,
        unsigned short* __restrict__ WT2,
        int* __restrict__ bucket_cursor,
        unsigned int* __restrict__ breg,
        int* __restrict__ flag) {
    __shared__ __align__(16) char smem[14336];
    int b = blockIdx.x, tid = threadIdx.x;
    if (b < 250) {
        unsigned int* ord = (unsigned int*)smem;             // 2560*4 = 10240
        int* hist  = (int*)(smem + 10240);
        int* start = hist + NBUCK;
        int* cur   = start + NBUCK;
        int* gbase = cur + NBUCK;
        int* sbuf  = gbase + NBUCK;
        int e0 = b * CHUNK;
        for (int i = tid; i < NBUCK; i += 256) hist[i] = 0;
        __syncthreads();
        unsigned int pk[10];
        int bk[10];
#pragma unroll
        for (int r = 0; r < 10; r++) {
            int e = e0 + r * 256 + tid;
            int s = __builtin_nontemporal_load(ei + e);
            int d = __builtin_nontemporal_load(ei + N_EDGES + e);
            int t = __builtin_nontemporal_load(et + e);
            pk[r] = (unsigned int)s | ((unsigned int)t << 15) | ((unsigned int)d << 17);
            bk[r] = d >> 7;
            atomicAdd(&hist[bk[r]], 1);
        }
        __syncthreads();
        int v = (tid < NBUCK) ? hist[tid] : 0;
        sbuf[tid] = v;
        __syncthreads();
        for (int o = 1; o < 256; o <<= 1) {
            int t = (tid >= o) ? sbuf[tid - o] : 0;
            __syncthreads();
            sbuf[tid] += t;
            __syncthreads();
        }
        if (tid < NBUCK) { start[tid] = sbuf[tid] - v; cur[tid] = sbuf[tid] - v; }
        __syncthreads();
#pragma unroll
        for (int r = 0; r < 10; r++) {
            int p = atomicAdd(&cur[bk[r]], 1);
            ord[p] = pk[r];
        }
        __syncthreads();
        for (int bb = tid; bb < NBUCK; bb += 256)
            if (hist[bb] > 0) gbase[bb] = atomicAdd(bucket_cursor + bb, hist[bb]);
        __syncthreads();
        for (int p = tid; p < CHUNK; p += 256) {
            unsigned int e = ord[p];
            int bb = (int)(e >> 24);
            int gp = gbase[bb] + (p - start[bb]);
            if (gp < BCAP)
                __builtin_nontemporal_store(e, breg + (size_t)bb * BCAP + gp);
        }
    } else if (b < 1500) {               // convx: bf16 copy + fp8 shadow
        int bf = local_flag((const unsigned short*)Ws1, (int*)smem);
        int idx = (b - 250) * 256 + tid;  // 8-elem chunk
        float f[8];
        if (bf) {
            uint4 v = reinterpret_cast<const uint4*>(x)[idx];
            reinterpret_cast<uint4*>(xc)[idx] = v;
            f[0] = bflo(v.x); f[1] = bfhi(v.x);
            f[2] = bflo(v.y); f[3] = bfhi(v.y);
            f[4] = bflo(v.z); f[5] = bfhi(v.z);
            f[6] = bflo(v.w); f[7] = bfhi(v.w);
        } else {
            const float* xf = reinterpret_cast<const float*>(x) + (size_t)idx * 8;
            unsigned short r[8] __attribute__((aligned(16)));
#pragma unroll
            for (int j = 0; j < 8; j++) { f[j] = xf[j]; r[j] = f2bf(xf[j]); }
            reinterpret_cast<uint4*>(xc)[idx] = *reinterpret_cast<const uint4*>(r);
        }
        int lo = 0, hi = 0;
        lo = __builtin_amdgcn_cvt_pk_fp8_f32(f[0], f[1], lo, false);
        lo = __builtin_amdgcn_cvt_pk_fp8_f32(f[2], f[3], lo, true);
        hi = __builtin_amdgcn_cvt_pk_fp8_f32(f[4], f[5], hi, false);
        hi = __builtin_amdgcn_cvt_pk_fp8_f32(f[6], f[7], hi, true);
        xc8[idx * 2]     = (unsigned int)lo;
        xc8[idx * 2 + 1] = (unsigned int)hi;
    } else if (b < 2140) {               // packW1
        int bf = local_flag((const unsigned short*)Ws1, (int*)smem);
        int idx = (b - 1500) * 256 + tid;
        int n = idx / 640, k = idx - n * 640;
        const void* p = (k < 128) ? Ws1 : Wt1;
        size_t src = (k < 128) ? ((size_t)k * 256 + n) : ((size_t)(k - 128) * 256 + n);
        WT1[idx] = bf ? ((const unsigned short*)p)[src] : f2bf(((const float*)p)[src]);
    } else if (b < 3420) {               // packW2
        int bf = local_flag((const unsigned short*)Ws1, (int*)smem);
        int idx = (b - 2140) * 256 + tid;
        int n = idx / 1280, k = idx - n * 1280;
        const void* p = (k < 256) ? Ws2 : Wt2;
        size_t src = (k < 256) ? ((size_t)k * 256 + n) : ((size_t)(k - 256) * 256 + n);
        WT2[idx] = bf ? ((const unsigned short*)p)[src] : f2bf(((const float*)p)[src]);
    } else {
        int bf = local_flag((const unsigned short*)Ws1, (int*)smem);
        if (tid == 0) *flag = bf;
    }
}

// Pass B: per-bucket counting sort -> perm + offsets4 (parallel scans).
__global__ __launch_bounds__(256) void bucketB_kernel(
        const unsigned int* __restrict__ breg,
        const int* __restrict__ bucket_cursor,
        unsigned short* __restrict__ perm,
        int* __restrict__ offsets4) {
    __shared__ int cnt[512], off[512];
    __shared__ int buf[256], pscan[256];
    int b = blockIdx.x, tid = threadIdx.x;
    int cv = (tid < NBUCK) ? bucket_cursor[tid] : 0;
    if (cv > BCAP) cv = BCAP;
    buf[tid] = cv;
    __syncthreads();
    for (int o = 1; o < 256; o <<= 1) {
        int t = (tid >= o) ? buf[tid - o] : 0;
        __syncthreads();
        buf[tid] += t;
        __syncthreads();
    }
    int obase = (b > 0) ? buf[b - 1] : 0;
    if (b == 0 && tid == 0) offsets4[NT4] = buf[255];
    int Eb = bucket_cursor[b];
    if (Eb > BCAP) Eb = BCAP;
    for (int i = tid; i < 512; i += 256) cnt[i] = 0;
    __syncthreads();
    const unsigned int* reg = breg + (size_t)b * BCAP;
    for (int i = tid; i < Eb; i += 256) {
        unsigned int e = reg[i];
        int seg = (((e >> 17) & 127) << 2) | ((e >> 15) & 3);
        atomicAdd(&cnt[seg], 1);
    }
    __syncthreads();
    int pv = cnt[2 * tid] + cnt[2 * tid + 1];
    pscan[tid] = pv;
    __syncthreads();
    for (int o = 1; o < 256; o <<= 1) {
        int t = (tid >= o) ? pscan[tid - o] : 0;
        __syncthreads();
        pscan[tid] += t;
        __syncthreads();
    }
    int pexcl = pscan[tid] - pv;
    off[2 * tid]     = pexcl;
    off[2 * tid + 1] = pexcl + cnt[2 * tid];
    __syncthreads();
    for (int i = tid; i < 512; i += 256) {
        int node = b * 128 + (i >> 2);
        if (node < N_NODES) offsets4[node * 4 + (i & 3)] = obase + off[i];
    }
    __syncthreads();
    for (int i = tid; i < Eb; i += 256) {
        unsigned int e = reg[i];
        int seg = (((e >> 17) & 127) << 2) | ((e >> 15) & 3);
        int p = atomicAdd(&off[seg], 1);
        perm[obase + p] = (unsigned short)(e & 0x7fff);
    }
}

// ---------- typed aggregation: fp8 gather, f32 accumulate ------------------
// R25: one (node,type) SEGMENT per G-lane subgroup + masked ILP8.
// R24 processed a node's 4 type-segments sequentially per subgroup (4
// dependent ~600cy LLC rounds; dynamic inner trip count blocks compiler
// pipelining across types). Decomposing to 80000 independent segment
// tasks removes that serialization: each task ~1 masked-ILP8 round,
// 4x more independent latency chains. T = 4n+t indexes offs4 directly;
// normalization still uses TOTAL node degree (offs4[4n],offs4[4n+4]).
static __device__ __forceinline__ void acc8(uint2 x, float* a) {
    v2f p0 = __builtin_amdgcn_cvt_pk_f32_fp8((int)x.x, false);
    v2f p1 = __builtin_amdgcn_cvt_pk_f32_fp8((int)x.x, true);
    v2f p2 = __builtin_amdgcn_cvt_pk_f32_fp8((int)x.y, false);
    v2f p3 = __builtin_amdgcn_cvt_pk_f32_fp8((int)x.y, true);
    a[0] += p0.x; a[1] += p0.y;
    a[2] += p1.x; a[3] += p1.y;
    a[4] += p2.x; a[5] += p2.y;
    a[6] += p3.x; a[7] += p3.y;
}

template <int D>
__global__ __launch_bounds__(256) void agg8_kernel(
        const unsigned int* __restrict__ F8,     // [N, D] fp8 (uint-chunked)
        const int* __restrict__ offs4,
        const unsigned short* __restrict__ perm,
        unsigned short* __restrict__ AG) {       // [N, 4*D] bf16
    constexpr int G = D / 8;                     // 16 (D=128) or 32 (D=256)
    constexpr int SGN = 64 / G;                  // 4 or 2 subgroups/wave
    int wave = threadIdx.x >> 6, lane = threadIdx.x & 63;
    int sg = lane / G;
    int gl = lane - sg * G;
    int sgid0   = (blockIdx.x * 4 + wave) * SGN + sg;
    int sstride = gridDim.x * 4 * SGN;
    for (int T = sgid0; T < NT4; T += sstride) {
        int n = T >> 2;
        int t = T & 3;
        int o0 = offs4[n * 4];
        int o4 = offs4[n * 4 + 4];
        int s0 = offs4[T];
        int s1 = offs4[T + 1];
        int deg = o4 - o0;
        float inv = 1.0f / (float)(deg > 1 ? deg : 1);
        float a[8];
#pragma unroll
        for (int v = 0; v < 8; v++) a[v] = 0.f;
        int j = s0;
        while (j < s1) {
            int m = s1 - j;
            if (m > G) m = G;                    // window = G edges
            int pw = (int)perm[j + ((gl < m) ? gl : 0)];
            for (int k = 0; k < m; k += 8) {     // masked ILP8
                uint2 x[8];
#pragma unroll
                for (int l = 0; l < 8; l++) {
                    int idx   = k + l;
                    int valid = (idx < m);
                    int src   = __shfl(pw, valid ? idx : (m - 1), G);
                    x[l] = *reinterpret_cast<const uint2*>(F8 + (size_t)src * (D / 4) + gl * 2);
                    unsigned msk = valid ? 0xffffffffu : 0u;  // fp8 0x00 == +0.0
                    x[l].x &= msk; x[l].y &= msk;
                }
#pragma unroll
                for (int l = 0; l < 8; l++) acc8(x[l], a);
            }
            j += m;
        }
        unsigned short r[8] __attribute__((aligned(16)));
#pragma unroll
        for (int v = 0; v < 8; v++) r[v] = f2bf(a[v] * inv);
        *reinterpret_cast<uint4*>(AG + (size_t)n * (4 * D) + t * D + gl * 8) =
            *reinterpret_cast<const uint4*>(r);
    }
}

// ---------- MFMA GEMM: C[M,256] = [X | AG] @ WT^T + bias -------------------
// R0 structure (best measured): 64x64 tile, XCD swizzle, LDW=72 padded LDS,
// grid 1280. Optional fp8 shadow emission of C (post-activation).
template <int D>
__global__ __launch_bounds__(256, 6) void gemm_kernel(
        const unsigned short* __restrict__ X,
        const unsigned short* __restrict__ AG,
        const unsigned short* __restrict__ BT,
        const void* __restrict__ bias,
        const int* __restrict__ flagp,
        unsigned short* __restrict__ C,
        unsigned char* __restrict__ C8,          // fp8 shadow (or nullptr)
        int M, int relu) {
    constexpr int K = 5 * D;
    constexpr int LDW = 72;
    __shared__ __align__(16) unsigned short As[64 * LDW];
    __shared__ __align__(16) unsigned short Bs[64 * LDW];
    int b = blockIdx.x;
    int mt = (b & 7) + 8 * (b >> 5);
    int nt = (b >> 3) & 3;
    int mtiles = (M + 63) >> 6;
    if (mt >= mtiles) return;
    int m0 = mt * 64;
    int n0 = nt * 64;
    int tid  = threadIdx.x;
    int wave = tid >> 6, lane = tid & 63;
    int wm = wave >> 1, wn = wave & 1;
    int quad = lane >> 4, l16 = lane & 15;

    f32x4 acc[2][2];
#pragma unroll
    for (int i = 0; i < 2; i++)
#pragma unroll
        for (int j = 0; j < 2; j++) acc[i][j] = (f32x4){0.f, 0.f, 0.f, 0.f};

    for (int k0 = 0; k0 < K; k0 += 64) {
        const unsigned short* base = (k0 < D) ? X : AG;
        int rs  = (k0 < D) ? D : 4 * D;
        int col = (k0 < D) ? k0 : (k0 - D);
#pragma unroll
        for (int cc = 0; cc < 2; cc++) {
            int c   = tid + cc * 256;
            int row = c >> 3;
            int c8  = c & 7;
            uint4 va = make_uint4(0u, 0u, 0u, 0u);
            int gr = m0 + row;
            if (gr < M)
                va = *reinterpret_cast<const uint4*>(base + (size_t)gr * rs + col + c8 * 8);
            *reinterpret_cast<uint4*>(&As[row * LDW + c8 * 8]) = va;
            uint4 vb = *reinterpret_cast<const uint4*>(BT + (size_t)(n0 + row) * K + k0 + c8 * 8);
            *reinterpret_cast<uint4*>(&Bs[row * LDW + c8 * 8]) = vb;
        }
        __syncthreads();
#pragma unroll
        for (int ks = 0; ks < 2; ks++) {
            v8bf af[2], bfr[2];
#pragma unroll
            for (int i = 0; i < 2; i++)
                af[i] = *reinterpret_cast<const v8bf*>(
                    &As[(wm * 32 + i * 16 + l16) * LDW + ks * 32 + quad * 8]);
#pragma unroll
            for (int j = 0; j < 2; j++)
                bfr[j] = *reinterpret_cast<const v8bf*>(
                    &Bs[(wn * 32 + j * 16 + l16) * LDW + ks * 32 + quad * 8]);
#pragma unroll
            for (int i = 0; i < 2; i++)
#pragma unroll
                for (int j = 0; j < 2; j++)
                    acc[i][j] = __builtin_amdgcn_mfma_f32_16x16x32_bf16(af[i], bfr[j], acc[i][j], 0, 0, 0);
        }
        __syncthreads();
    }
    int bf = *flagp;
#pragma unroll
    for (int i = 0; i < 2; i++) {
#pragma unroll
        for (int j = 0; j < 2; j++) {
            int col = n0 + wn * 32 + j * 16 + l16;
            float bv = bf ? bf2f(((const unsigned short*)bias)[col])
                          : ((const float*)bias)[col];
#pragma unroll
            for (int r = 0; r < 4; r++) {
                int row = m0 + wm * 32 + i * 16 + quad * 4 + r;
                if (row < M) {
                    float v = acc[i][j][r] + bv;
                    if (relu) v = fmaxf(v, 0.0f);
                    C[(size_t)row * 256 + col] = f2bf(v);
                    if (C8) {
                        int pk = __builtin_amdgcn_cvt_pk_fp8_f32(v, v, 0, false);
                        C8[(size_t)row * 256 + col] = (unsigned char)(pk & 0xff);
                    }
                }
            }
        }
    }
}

// ---------- classifier head ------------------------------------------------
__global__ void cls_kernel(const unsigned short* __restrict__ h2,
                           const int* __restrict__ aidx,
                           const void* __restrict__ Wc,
                           const void* __restrict__ bc,
                           const int* __restrict__ flagp,
                           void* __restrict__ out) {
    int lin = blockIdx.x * blockDim.x + threadIdx.x;
    int a = lin >> 6, lane = lin & 63;
    if (a >= N_ASPECTS) return;
    int bf = *flagp;
    int node = aidx[a];
    uint2 v = *reinterpret_cast<const uint2*>(h2 + (size_t)node * 256 + lane * 4);
    float hv[4] = {bflo(v.x), bfhi(v.x), bflo(v.y), bfhi(v.y)};
    float a0 = 0.f, a1 = 0.f, a2 = 0.f;
#pragma unroll
    for (int r = 0; r < 4; r++) {
        int k = lane * 4 + r;
        float w0 = bf ? bf2f(((const unsigned short*)Wc)[k * 3 + 0]) : ((const float*)Wc)[k * 3 + 0];
        float w1 = bf ? bf2f(((const unsigned short*)Wc)[k * 3 + 1]) : ((const float*)Wc)[k * 3 + 1];
        float w2 = bf ? bf2f(((const unsigned short*)Wc)[k * 3 + 2]) : ((const float*)Wc)[k * 3 + 2];
        a0 += hv[r] * w0;
        a1 += hv[r] * w1;
        a2 += hv[r] * w2;
    }
#pragma unroll
    for (int off = 32; off >= 1; off >>= 1) {
        a0 += __shfl_down(a0, off);
        a1 += __shfl_down(a1, off);
        a2 += __shfl_down(a2, off);
    }
    if (lane == 0) {
        float b0 = bf ? bf2f(((const unsigned short*)bc)[0]) : ((const float*)bc)[0];
        float b1 = bf ? bf2f(((const unsigned short*)bc)[1]) : ((const float*)bc)[1];
        float b2 = bf ? bf2f(((const unsigned short*)bc)[2]) : ((const float*)bc)[2];
        if (bf) {
            unsigned short* o = (unsigned short*)out;
            o[a * 3 + 0] = f2bf(a0 + b0);
            o[a * 3 + 1] = f2bf(a1 + b1);
            o[a * 3 + 2] = f2bf(a2 + b2);
        } else {
            float* o = (float*)out;
            o[a * 3 + 0] = a0 + b0;
            o[a * 3 + 1] = a1 + b1;
            o[a * 3 + 2] = a2 + b2;
        }
    }
}

extern "C" void kernel_launch(void* const* d_in, const int* in_sizes, int n_in,
                              void* d_out, int out_size, void* d_ws, size_t ws_size,
                              hipStream_t stream) {
    const void* x   = d_in[0];
    const void* Wt1 = d_in[1];
    const void* Ws1 = d_in[2];
    const void* b1  = d_in[3];
    const void* Wt2 = d_in[4];
    const void* Ws2 = d_in[5];
    const void* b2  = d_in[6];
    const void* Wc  = d_in[7];
    const void* bc  = d_in[8];
    const int* ei = (const int*)d_in[9];
    const int* et = (const int*)d_in[10];
    const int* ai = (const int*)d_in[11];

    char* ws = (char*)d_ws;
    size_t off = 0;
    auto alloc = [&](size_t bytes) {
        void* p = ws + off;
        off += (bytes + 255) & ~(size_t)255;
        return p;
    };
    int*            flag          = (int*)alloc(4);
    int*            bucket_cursor = (int*)alloc((size_t)NBUCK * 4);
    int*            offsets4      = (int*)alloc((size_t)(NT4 + 1) * 4);
    unsigned int*   breg          = (unsigned int*)alloc((size_t)NBUCK * BCAP * 4); // 3.2 MB
    unsigned short* perm          = (unsigned short*)alloc((size_t)N_EDGES * 2);
    unsigned short* xc            = (unsigned short*)alloc((size_t)N_NODES * IN_DIM * 2);
    unsigned int*   xc8           = (unsigned int*)alloc((size_t)N_NODES * IN_DIM);    // 2.6 MB fp8
    unsigned short* AG            = (unsigned short*)alloc((size_t)N_NODES * 4 * HID_DIM * 2);
    unsigned short* h             = (unsigned short*)alloc((size_t)N_NODES * HID_DIM * 2);
    unsigned char*  h8            = (unsigned char*)alloc((size_t)N_NODES * HID_DIM);  // 5.1 MB fp8
    unsigned short* h2            = (unsigned short*)alloc((size_t)N_NODES * HID_DIM * 2);
    unsigned short* WT1           = (unsigned short*)alloc((size_t)640 * 256 * 2);
    unsigned short* WT2           = (unsigned short*)alloc((size_t)1280 * 256 * 2);
    // total ~60 MB

    hipMemsetAsync(bucket_cursor, 0, (size_t)NBUCK * 4, stream);
    prepA_kernel<<<3421, 256, 0, stream>>>(x, Ws1, Wt1, Ws2, Wt2, ei, et,
                                           xc, xc8, WT1, WT2, bucket_cursor, breg, flag);
    bucketB_kernel<<<NBUCK, 256, 0, stream>>>(breg, bucket_cursor, perm, offsets4);

    // Layer 1 (fp8 gather on x; self-term X stays bf16)
    agg8_kernel<IN_DIM><<<4096, 256, 0, stream>>>(xc8, offsets4, perm, AG);
    gemm_kernel<IN_DIM><<<1280, 256, 0, stream>>>(xc, AG, WT1, b1, flag, h, h8, N_NODES, 1);
    // Layer 2 (fp8 shadow emitted by gemm1's epilogue)
    agg8_kernel<HID_DIM><<<4096, 256, 0, stream>>>((const unsigned int*)h8, offsets4, perm, AG);
    gemm_kernel<HID_DIM><<<1280, 256, 0, stream>>>(h, AG, WT2, b2, flag, h2, nullptr, N_NODES, 0);
    // Head
    cls_kernel<<<(N_ASPECTS * 64) / 256, 256, 0, stream>>>(h2, ai, Wc, bc, flag, d_out);
}